// Round 9
// baseline (335.327 us; speedup 1.0000x reference)
//
#include <hip/hip_runtime.h>
#include <hip/hip_bf16.h>
#include <math.h>

typedef __hip_bfloat16 bf16;

// Problem constants
constexpr int B_   = 2;
constexpr int T_   = 8;
constexpr int HW   = 48 * 48;          // 2304
constexpr int S_   = T_ * HW;          // 18432
constexpr int D_   = 64;
constexpr int NH   = 4;
constexpr int DH   = 16;
constexpr int M_   = 32;
constexpr int BS   = B_ * S_;          // 36864 tokens
constexpr int BSD  = BS * D_;          // 2359296
constexpr int BH   = B_ * NH;          // 8 sequences
constexpr int BHS  = BH * S_;          // 147456 rows
constexpr int BHSM = BHS * M_;         // 4718592
constexpr int CHUNK = 32;
constexpr int NC   = S_ / CHUNK;       // 576 chunks per sequence
constexpr int STATE = M_ * DH + M_;    // 544 floats of scan state
constexpr float DN = 0.5f;                         // 16^-0.25
constexpr float RATIO = 0.17677669529663687f;      // 32^-0.5

__device__ __forceinline__ unsigned short f2bf(float f) {
  bf16 h = __float2bfloat16(f);
  return *reinterpret_cast<unsigned short*>(&h);
}

// ---------------- fused: 1x1x1 conv3d + softplus + LayerNorm1 ----------------
__global__ void k_preln(const float* __restrict__ x, const float* __restrict__ pw,
                        const float* __restrict__ pb, const float* __restrict__ g,
                        const float* __restrict__ bb,
                        float* __restrict__ tok, float* __restrict__ h) {
  int token = blockIdx.x * 4 + (threadIdx.x >> 6);
  int lane = threadIdx.x & 63;
  int f = token * 64 + lane;          // flat over B*D*S
  int b = f / (D_ * S_);
  int r = f % (D_ * S_);
  int d = r / S_;
  int pos = r % S_;
  const float* xb = x + b * 3 * S_ + pos;
  float a = xb[0] * pw[d * 3 + 0] + xb[S_] * pw[d * 3 + 1] + xb[2 * S_] * pw[d * 3 + 2]
          + pb[d];
  float t = fmaxf(a, 0.f) + log1pf(expf(-fabsf(a)));  // softplus
  tok[f] = t;
  float s1 = t, s2 = t * t;
  for (int off = 32; off; off >>= 1) {
    s1 += __shfl_xor(s1, off);
    s2 += __shfl_xor(s2, off);
  }
  float mu = s1 * (1.f / 64.f);
  float var = s2 * (1.f / 64.f) - mu * mu;
  float rs = rsqrtf(var + 1e-5f);
  h[f] = (t - mu) * rs * g[lane] + bb[lane];
}

// ---------------- QKV projections, register-tiled: q,k,v in [BH][S][16] ----------------
__global__ void __launch_bounds__(256) k_qkv(const float* __restrict__ h,
                      const float* __restrict__ wq, const float* __restrict__ wk,
                      const float* __restrict__ wv,
                      float* __restrict__ q, float* __restrict__ k, float* __restrict__ v) {
  __shared__ __align__(16) float sH[32 * 68];
  int tid = threadIdx.x;
  int tbase = blockIdx.x * 32;
  for (int e = tid; e < 512; e += 256) {
    int row = e >> 4, c4 = e & 15;
    *(float4*)&sH[row * 68 + c4 * 4] = *(const float4*)&h[(tbase + row) * 64 + c4 * 4];
  }
  __syncthreads();
  int tg = tid >> 6;        // 4 groups of 8 tokens
  int cg = tid & 63;        // output col
  float aq[8], ak[8], av[8];
#pragma unroll
  for (int i = 0; i < 8; ++i) { aq[i] = 0.f; ak[i] = 0.f; av[i] = 0.f; }
  for (int dc = 0; dc < 16; ++dc) {
    float4 hf[8];
#pragma unroll
    for (int i = 0; i < 8; ++i) hf[i] = *(const float4*)&sH[(tg * 8 + i) * 68 + dc * 4];
    float wqv[4], wkv[4], wvv[4];
#pragma unroll
    for (int dd = 0; dd < 4; ++dd) {
      int d = dc * 4 + dd;
      wqv[dd] = wq[d * 64 + cg]; wkv[dd] = wk[d * 64 + cg]; wvv[dd] = wv[d * 64 + cg];
    }
#pragma unroll
    for (int i = 0; i < 8; ++i) {
      const float* hp = (const float*)&hf[i];
#pragma unroll
      for (int dd = 0; dd < 4; ++dd) {
        aq[i] += hp[dd] * wqv[dd];
        ak[i] += hp[dd] * wkv[dd];
        av[i] += hp[dd] * wvv[dd];
      }
    }
  }
  int head = cg >> 4, di = cg & 15;
#pragma unroll
  for (int i = 0; i < 8; ++i) {
    int token = tbase + tg * 8 + i;
    int b = token / S_, s = token % S_;
    int o = ((b * NH + head) * S_ + s) * DH + di;
    q[o] = aq[i]; k[o] = ak[i]; v[o] = av[i];
  }
}

// ---------------- feature map, row-per-thread: qp final + raw dash_k + diag_k + block max ----------------
__global__ void __launch_bounds__(64) k_feat(const float* __restrict__ q,
                      const float* __restrict__ k, const float* __restrict__ proj,
                      float* __restrict__ qp, float* __restrict__ kp,
                      float* __restrict__ diagk, float* __restrict__ part) {
  __shared__ __align__(16) float sPT[16 * 32];   // proj^T [d][m]
  int tid = threadIdx.x;
  for (int e = tid; e < 512; e += 64) {
    int d = e >> 5, m = e & 31;
    sPT[d * 32 + m] = proj[m * 16 + d];          // m-fastest write: conflict-free
  }
  __syncthreads();
  int row = blockIdx.x * 64 + tid;
  float qv[16], kv[16];
  float dq = 0.f, dk = 0.f;
  {
    const float4* q4 = (const float4*)(q + (size_t)row * 16);
    const float4* k4 = (const float4*)(k + (size_t)row * 16);
#pragma unroll
    for (int i = 0; i < 4; ++i) {
      float4 t4 = q4[i];
      qv[4*i] = t4.x * DN; qv[4*i+1] = t4.y * DN; qv[4*i+2] = t4.z * DN; qv[4*i+3] = t4.w * DN;
      float4 u4 = k4[i];
      kv[4*i] = u4.x * DN; kv[4*i+1] = u4.y * DN; kv[4*i+2] = u4.z * DN; kv[4*i+3] = u4.w * DN;
    }
#pragma unroll
    for (int d = 0; d < 16; ++d) { dq += qv[d] * qv[d]; dk += kv[d] * kv[d]; }
    dq *= 0.5f; dk *= 0.5f;
  }
  float accq[32], acck[32];
#pragma unroll
  for (int m = 0; m < 32; ++m) { accq[m] = 0.f; acck[m] = 0.f; }
#pragma unroll
  for (int d = 0; d < 16; ++d) {
    float qd = qv[d], kd = kv[d];
    const float4* pr = (const float4*)&sPT[d * 32];
#pragma unroll
    for (int m4 = 0; m4 < 8; ++m4) {
      float4 p = pr[m4];                          // wave-uniform address: broadcast
      accq[4*m4+0] += qd * p.x; accq[4*m4+1] += qd * p.y;
      accq[4*m4+2] += qd * p.z; accq[4*m4+3] += qd * p.w;
      acck[4*m4+0] += kd * p.x; acck[4*m4+1] += kd * p.y;
      acck[4*m4+2] += kd * p.z; acck[4*m4+3] += kd * p.w;
    }
  }
  float mx = accq[0];
#pragma unroll
  for (int m = 1; m < 32; ++m) mx = fmaxf(mx, accq[m]);
#pragma unroll
  for (int m4 = 0; m4 < 8; ++m4) {
    float4 o;
    o.x = RATIO * (expf(accq[4*m4+0] - dq - mx) + 1e-4f);
    o.y = RATIO * (expf(accq[4*m4+1] - dq - mx) + 1e-4f);
    o.z = RATIO * (expf(accq[4*m4+2] - dq - mx) + 1e-4f);
    o.w = RATIO * (expf(accq[4*m4+3] - dq - mx) + 1e-4f);
    *(float4*)&qp[(size_t)row * 32 + m4 * 4] = o;
  }
  float bmax = acck[0];
#pragma unroll
  for (int m = 1; m < 32; ++m) bmax = fmaxf(bmax, acck[m]);
#pragma unroll
  for (int m4 = 0; m4 < 8; ++m4)
    *(float4*)&kp[(size_t)row * 32 + m4 * 4] = *(float4*)&acck[4 * m4];
  diagk[row] = dk;
  for (int off = 32; off; off >>= 1) bmax = fmaxf(bmax, __shfl_xor(bmax, off));
  if (tid == 0) part[blockIdx.x] = bmax;
}

__global__ void k_maxred(const float* __restrict__ part, float* __restrict__ gmax) {
  float m = -3.4e38f;
  for (int i = threadIdx.x; i < BHS / 64; i += 256) m = fmaxf(m, part[i]);
  __shared__ float red[256];
  red[threadIdx.x] = m;
  __syncthreads();
  for (int s = 128; s; s >>= 1) {
    if (threadIdx.x < s) red[threadIdx.x] = fmaxf(red[threadIdx.x], red[threadIdx.x + s]);
    __syncthreads();
  }
  if (!threadIdx.x) gmax[0] = red[0];
}

// ---------------- kp-finalize + per-chunk sums; accumulation from L1-hot global ----------------
__global__ void __launch_bounds__(256) k_csfin(const float* __restrict__ diagk,
                      const float* __restrict__ gmax, const float* __restrict__ v,
                      float* __restrict__ kp, float* __restrict__ ckv) {
  int blk = blockIdx.x;
  int bh = blk / NC, c = blk % NC;
  int tid = threadIdx.x;
  int base = bh * S_ + c * CHUNK;
  float gm = gmax[0];
  {
    int row = tid >> 3, m4 = tid & 7;            // 32 rows x 8 float4
    float4 dash = *(const float4*)&kp[(size_t)(base + row) * 32 + m4 * 4];
    float dg = diagk[base + row] + gm;
    float4 fin;
    fin.x = RATIO * (expf(dash.x - dg) + 1e-4f);
    fin.y = RATIO * (expf(dash.y - dg) + 1e-4f);
    fin.z = RATIO * (expf(dash.z - dg) + 1e-4f);
    fin.w = RATIO * (expf(dash.w - dg) + 1e-4f);
    *(float4*)&kp[(size_t)(base + row) * 32 + m4 * 4] = fin;
  }
  __syncthreads();   // block-level global visibility (CUDA/HIP semantics)
  int m0 = tid >> 4, d0 = tid & 15;
  int m1 = m0 + 16;
  float a0 = 0.f, a1 = 0.f, az0 = 0.f, az1 = 0.f;
  for (int t = 0; t < CHUNK; ++t) {
    const float* kr = kp + (size_t)(base + t) * 32;
    float k0 = kr[m0];
    float k1 = kr[m1];
    float vv = v[(size_t)(base + t) * 16 + d0];
    a0 += k0 * vv;
    a1 += k1 * vv;
    if (d0 == 0) { az0 += k0; az1 += k1; }
  }
  float* outp = ckv + (size_t)blk * STATE;
  outp[m0 * 16 + d0] = a0;
  outp[m1 * 16 + d0] = a1;
  if (d0 == 0) { outp[512 + m0] = az0; outp[512 + m1] = az1; }
}

// ---------------- exclusive prefix over chunks (in place), one scan-column per thread ----------------
__global__ void k_prefix(float* __restrict__ ckv) {
  int idx = blockIdx.x * 256 + threadIdx.x;      // 17 blocks x 256 = 4352 = BH*544
  int bh = idx / STATE, c = idx % STATE;
  float run = 0.f;
  for (int j0 = 0; j0 < NC; j0 += 16) {
    float tb[16];
#pragma unroll
    for (int jj = 0; jj < 16; ++jj) tb[jj] = ckv[((size_t)bh * NC + j0 + jj) * STATE + c];
#pragma unroll
    for (int jj = 0; jj < 16; ++jj) {
      ckv[((size_t)bh * NC + j0 + jj) * STATE + c] = run;
      run += tb[jj];
    }
  }
}

// ---------------- within-chunk causal attention (CHUNK=32, 1 wave); K/V via L1 ----------------
__global__ void __launch_bounds__(64) k_attn(const float* __restrict__ qp,
                                             const float* __restrict__ kp,
                                             const float* __restrict__ v,
                                             const float* __restrict__ ckv,
                                             float* __restrict__ attn) {
  __shared__ __align__(16) float sS[512];
  __shared__ __align__(16) float sz[32];
  int blk = blockIdx.x;
  int bh = blk / NC, c = blk % NC;
  int tid = threadIdx.x;
  int base = bh * S_ + c * CHUNK;

  const float* cs = ckv + (size_t)blk * STATE;
  for (int e = tid; e < 136; e += 64) {
    if (e < 128) *(float4*)&sS[e * 4] = *(const float4*)&cs[e * 4];
    else *(float4*)&sz[(e - 128) * 4] = *(const float4*)&cs[512 + (e - 128) * 4];
  }
  __syncthreads();

  int srow = tid >> 1, h = tid & 1;   // 2 threads per output row
  float q[32];
  {
    const float4* q4 = (const float4*)(qp + (size_t)(base + srow) * M_);
#pragma unroll
    for (int i = 0; i < 8; ++i) {
      float4 t4 = q4[i];
      q[4 * i] = t4.x; q[4 * i + 1] = t4.y; q[4 * i + 2] = t4.z; q[4 * i + 3] = t4.w;
    }
  }
  float n[16];
#pragma unroll
  for (int d = 0; d < 16; ++d) n[d] = 0.f;
  float den = 0.f;
  for (int t = h; t <= srow; t += 2) {
    const float4* kr = (const float4*)(kp + (size_t)(base + t) * M_);
    float a = 0.f;
#pragma unroll
    for (int i = 0; i < 8; ++i) {
      float4 kk = kr[i];
      a += q[4 * i] * kk.x + q[4 * i + 1] * kk.y + q[4 * i + 2] * kk.z + q[4 * i + 3] * kk.w;
    }
    den += a;
    const float4* vr = (const float4*)(v + (size_t)(base + t) * DH);
#pragma unroll
    for (int i = 0; i < 4; ++i) {
      float4 vv = vr[i];
      n[4 * i] += a * vv.x; n[4 * i + 1] += a * vv.y;
      n[4 * i + 2] += a * vv.z; n[4 * i + 3] += a * vv.w;
    }
  }
  // carry-in state, split across the thread pair (h half of m)
#pragma unroll
  for (int mm = 0; mm < 16; ++mm) {
    int m = h * 16 + mm;
    den += q[m] * sz[m];
    const float4* sr = (const float4*)(sS + m * 16);
#pragma unroll
    for (int j = 0; j < 4; ++j) {
      float4 sv = sr[j];
      n[4 * j] += q[m] * sv.x; n[4 * j + 1] += q[m] * sv.y;
      n[4 * j + 2] += q[m] * sv.z; n[4 * j + 3] += q[m] * sv.w;
    }
  }
  den += __shfl_xor(den, 1);
#pragma unroll
  for (int d = 0; d < 16; ++d) n[d] += __shfl_xor(n[d], 1);
  float rden = 1.f / den;
  int b = bh >> 2, head = bh & 3;
  int s_glob = c * CHUNK + srow;
  float* orow = attn + ((size_t)(b * S_ + s_glob)) * 64 + head * 16;
#pragma unroll
  for (int d = 0; d < 16; ++d) {
    if ((d >> 3) == h) orow[d] = n[d] * rden;
  }
}

// ---------------- attn @ wo + bo + residual + LayerNorm2, fused ----------------
__global__ void __launch_bounds__(256) k_wo_ln(const float* __restrict__ attn,
                        const float* __restrict__ wo, const float* __restrict__ bo,
                        const float* __restrict__ tok, const float* __restrict__ g,
                        const float* __restrict__ bb,
                        float* __restrict__ tok2, float* __restrict__ h2) {
  __shared__ __align__(16) float sA[32 * 68];
  int tid = threadIdx.x;
  int tbase = blockIdx.x * 32;
  for (int e = tid; e < 512; e += 256) {
    int row = e >> 4, c4 = e & 15;
    *(float4*)&sA[row * 68 + c4 * 4] = *(const float4*)&attn[(tbase + row) * 64 + c4 * 4];
  }
  __syncthreads();
  int tg = tid >> 5;
  int cg = tid & 31;
  int c0 = cg * 2, c1 = c0 + 1;
  float a0[4], a1[4];
#pragma unroll
  for (int i = 0; i < 4; ++i) { a0[i] = 0.f; a1[i] = 0.f; }
  for (int dc = 0; dc < 16; ++dc) {
    float4 af[4];
#pragma unroll
    for (int i = 0; i < 4; ++i) af[i] = *(const float4*)&sA[(tg * 4 + i) * 68 + dc * 4];
    float w0[4], w1v[4];
#pragma unroll
    for (int dd = 0; dd < 4; ++dd) {
      int d = dc * 4 + dd;
      w0[dd] = wo[d * 64 + c0]; w1v[dd] = wo[d * 64 + c1];
    }
#pragma unroll
    for (int i = 0; i < 4; ++i) {
      const float* ap = (const float*)&af[i];
#pragma unroll
      for (int dd = 0; dd < 4; ++dd) { a0[i] += ap[dd] * w0[dd]; a1[i] += ap[dd] * w1v[dd]; }
    }
  }
  float bo0 = bo[c0], bo1 = bo[c1];
  float g0 = g[c0], g1 = g[c1], be0 = bb[c0], be1 = bb[c1];
#pragma unroll
  for (int i = 0; i < 4; ++i) {
    int token = tbase + tg * 4 + i;
    float t0 = tok[token * 64 + c0] + a0[i] + bo0;
    float t1 = tok[token * 64 + c1] + a1[i] + bo1;
    float s1 = t0 + t1, s2 = t0 * t0 + t1 * t1;
    for (int off = 16; off; off >>= 1) {
      s1 += __shfl_xor(s1, off, 32);
      s2 += __shfl_xor(s2, off, 32);
    }
    float mu = s1 * (1.f / 64.f);
    float var = s2 * (1.f / 64.f) - mu * mu;
    float rs = rsqrtf(var + 1e-5f);
    tok2[token * 64 + c0] = t0;
    tok2[token * 64 + c1] = t1;
    h2[token * 64 + c0] = (t0 - mu) * rs * g0 + be0;
    h2[token * 64 + c1] = (t1 - mu) * rs * g1 + be1;
  }
}

// ---------------- FF phase 1: G = gelu(h2 @ W1 + b1), bf16 out ----------------
__global__ void __launch_bounds__(256) k_ff1(const float* __restrict__ h2,
                                             const float* __restrict__ w1,
                                             const float* __restrict__ b1,
                                             bf16* __restrict__ G) {
  __shared__ __align__(16) float sH[64 * 68];   // 17.4 KB
  int tid = threadIdx.x;
  int tbase = blockIdx.x * 64;
  for (int e = tid; e < 1024; e += 256) {
    int row = e >> 4, c4 = e & 15;
    *(float4*)&sH[row * 68 + c4 * 4] = *(const float4*)&h2[(size_t)(tbase + row) * 64 + c4 * 4];
  }
  __syncthreads();
  int tg = tid >> 5;        // 8 groups of 8 tokens
  int cg = tid & 31;        // 8 cols each: cg*8..+7
  float acc[8][8];
#pragma unroll
  for (int i = 0; i < 8; ++i)
#pragma unroll
    for (int j = 0; j < 8; ++j) acc[i][j] = 0.f;
  for (int dc = 0; dc < 16; ++dc) {
    float4 hf[8];
#pragma unroll
    for (int i = 0; i < 8; ++i) hf[i] = *(const float4*)&sH[(tg * 8 + i) * 68 + dc * 4];
    float4 wa[4], wb[4];
#pragma unroll
    for (int dd = 0; dd < 4; ++dd) {
      int d = dc * 4 + dd;
      wa[dd] = *(const float4*)&w1[d * 256 + cg * 8];
      wb[dd] = *(const float4*)&w1[d * 256 + cg * 8 + 4];
    }
#pragma unroll
    for (int i = 0; i < 8; ++i) {
      const float* hp = (const float*)&hf[i];
#pragma unroll
      for (int dd = 0; dd < 4; ++dd) {
        float hv = hp[dd];
        const float* pa = (const float*)&wa[dd];
        const float* pb = (const float*)&wb[dd];
        acc[i][0] += hv * pa[0]; acc[i][1] += hv * pa[1];
        acc[i][2] += hv * pa[2]; acc[i][3] += hv * pa[3];
        acc[i][4] += hv * pb[0]; acc[i][5] += hv * pb[1];
        acc[i][6] += hv * pb[2]; acc[i][7] += hv * pb[3];
      }
    }
  }
  float bv[8];
  *(float4*)&bv[0] = *(const float4*)&b1[cg * 8];
  *(float4*)&bv[4] = *(const float4*)&b1[cg * 8 + 4];
#pragma unroll
  for (int i = 0; i < 8; ++i) {
    unsigned int pk[4];
#pragma unroll
    for (int j = 0; j < 4; ++j) {
      float x0 = acc[i][2 * j] + bv[2 * j];
      float x1 = acc[i][2 * j + 1] + bv[2 * j + 1];
      float g0 = 0.5f * x0 * (1.f + erff(x0 * 0.70710678118654752f));
      float g1 = 0.5f * x1 * (1.f + erff(x1 * 0.70710678118654752f));
      pk[j] = (unsigned int)f2bf(g0) | ((unsigned int)f2bf(g1) << 16);
    }
    int token = tbase + tg * 8 + i;
    *(uint4*)&G[(size_t)token * 256 + cg * 8] = *(uint4*)&pk[0];
  }
}

// ---------------- Gavg: mean over T of the 8 G rows feeding each pool element ----------------
__global__ void k_gavg(const bf16* __restrict__ G, float* __restrict__ Gavg) {
  int blk = blockIdx.x;                 // 4608 = B*64*36
  int tid = threadIdx.x;                // column 0..255
  int b = blk / 2304;
  int rem = blk % 2304;
  int ch = rem / 36, jp = rem % 36;
  size_t gbase = ((size_t)b * 18432 + ch * 288 + jp) * 256 + tid;
  float s = 0.f;
#pragma unroll
  for (int t = 0; t < 8; ++t) s += __bfloat162float(G[gbase + (size_t)t * 36 * 256]);
  Gavg[(size_t)blk * 256 + tid] = s * 0.125f;
}

// ---------------- pool = mean_t(tok2) + Gavg @ W2 + b2 (FF2 folded 8x by linearity) ----------------
__global__ void __launch_bounds__(256) k_pool2(const float* __restrict__ Gavg,
                        const float* __restrict__ tok2, const float* __restrict__ w2,
                        const float* __restrict__ b2, float* __restrict__ pool) {
  __shared__ __align__(16) float sG[18 * 256];     // 18.4 KB
  __shared__ __align__(16) float sRed[4 * 18 * 64]; // 18.4 KB
  int blk = blockIdx.x;
  int b = blk / 128;
  int rem = blk % 128;
  int ch = rem >> 1, jph = rem & 1;
  int tid = threadIdx.x;
  size_t grow0 = ((size_t)(b * 64 + ch) * 36 + jph * 18) * 256;
  for (int e = tid; e < 1152; e += 256) {          // 18 rows x 64 float4
    int row = e >> 6, c4 = e & 63;
    *(float4*)&sG[row * 256 + c4 * 4] = *(const float4*)&Gavg[grow0 + row * 256 + c4 * 4];
  }
  __syncthreads();
  int kg = tid >> 6, dd = tid & 63;
  float acc[18];
#pragma unroll
  for (int i = 0; i < 18; ++i) acc[i] = 0.f;
  for (int k4 = 0; k4 < 16; ++k4) {
    int k = kg * 64 + k4 * 4;
    float w0 = w2[(k + 0) * 64 + dd];
    float w1 = w2[(k + 1) * 64 + dd];
    float w2v = w2[(k + 2) * 64 + dd];
    float w3 = w2[(k + 3) * 64 + dd];
#pragma unroll
    for (int i = 0; i < 18; ++i) {
      float4 gf = *(const float4*)&sG[i * 256 + k];   // wave-wide broadcast
      acc[i] += gf.x * w0 + gf.y * w1 + gf.z * w2v + gf.w * w3;
    }
  }
#pragma unroll
  for (int i = 0; i < 18; ++i) sRed[(kg * 18 + i) * 64 + dd] = acc[i];
  __syncthreads();
  for (int o = tid; o < 1152; o += 256) {
    int jp18 = o >> 6, d2 = o & 63;
    float gsum = sRed[(0 * 18 + jp18) * 64 + d2] + sRed[(1 * 18 + jp18) * 64 + d2]
               + sRed[(2 * 18 + jp18) * 64 + d2] + sRed[(3 * 18 + jp18) * 64 + d2];
    int p = (jph * 18 + jp18) * 64 + d2;
    size_t tbase = (size_t)b * 1179648 + (size_t)ch * 18432 + p;
    float ts = 0.f;
#pragma unroll
    for (int t = 0; t < 8; ++t) ts += tok2[tbase + t * 2304];
    pool[((size_t)(b * 64 + ch)) * HW + p] = ts * 0.125f + gsum + b2[d2];
  }
}

// ---------------- conv(5x5,pad2) + global-avg-pool folded ----------------
__global__ void __launch_bounds__(256) k_convsum(const float* __restrict__ pool,
                                                 const float* __restrict__ x,
                                                 const float* __restrict__ w,
                                                 float* __restrict__ partial) {
  int blk = blockIdx.x;          // b*65 + ch
  int b = blk / 65, ch = blk % 65;
  int tid = threadIdx.x;
  __shared__ float cls[25];
  __shared__ float red[256];
  if (tid < 25) {
    int ry = tid / 5, rx = tid % 5;
    int kh0 = (ry <= 2) ? 0 : (ry == 3 ? 1 : 2);
    int kh1 = (ry >= 2) ? 4 : (ry == 1 ? 3 : 2);
    int kw0 = (rx <= 2) ? 0 : (rx == 3 ? 1 : 2);
    int kw1 = (rx >= 2) ? 4 : (rx == 1 ? 3 : 2);
    float s = 0.f;
    for (int kh = kh0; kh <= kh1; ++kh)
      for (int kw = kw0; kw <= kw1; ++kw)
        s += w[ch * 25 + kh * 5 + kw];
    cls[tid] = s;
  }
  __syncthreads();
  const float* pc = (ch < 64) ? (pool + ((size_t)(b * 64 + ch)) * HW)
                              : (x + (size_t)b * 3 * S_ + 2 * S_);
  float acc = 0.f;
#pragma unroll
  for (int e = tid; e < HW; e += 256) {
    int iy = e / 48, ix = e % 48;
    int ry = (iy == 0) ? 0 : (iy == 1) ? 1 : (iy <= 45) ? 2 : (iy == 46) ? 3 : 4;
    int rx = (ix == 0) ? 0 : (ix == 1) ? 1 : (ix <= 45) ? 2 : (ix == 46) ? 3 : 4;
    acc += pc[e] * cls[ry * 5 + rx];
  }
  red[tid] = acc;
  __syncthreads();
  for (int s = 128; s; s >>= 1) {
    if (tid < s) red[tid] += red[tid + s];
    __syncthreads();
  }
  if (!tid) partial[blk] = red[0];
}

// ---------------- reduce 65 channel sums per b + readout ----------------
__global__ void k_final(const float* __restrict__ partial, const float* __restrict__ tgt_b,
                        const float* __restrict__ rd_w, const float* __restrict__ rd_b,
                        float* __restrict__ out) {
  int b = blockIdx.x;
  int lane = threadIdx.x;
  float s = (lane < 65) ? partial[b * 65 + lane] : 0.f;
  for (int off = 32; off; off >>= 1) s += __shfl_down(s, off, 64);
  __shared__ float r2;
  if (lane == 64) r2 = s;
  __syncthreads();
  if (!lane) {
    float tot = s + r2;
    float mean = tot / 2304.f + tgt_b[0];
    out[b] = mean * rd_w[0] + rd_b[0];
  }
}

extern "C" void kernel_launch(void* const* d_in, const int* in_sizes, int n_in,
                              void* d_out, int out_size, void* d_ws, size_t ws_size,
                              hipStream_t stream) {
  const float* x     = (const float*)d_in[0];
  const float* pre_w = (const float*)d_in[1];
  const float* pre_b = (const float*)d_in[2];
  const float* ln1_g = (const float*)d_in[3];
  const float* ln1_b = (const float*)d_in[4];
  const float* wq    = (const float*)d_in[5];
  const float* wk    = (const float*)d_in[6];
  const float* wv    = (const float*)d_in[7];
  const float* wo    = (const float*)d_in[8];
  const float* bo    = (const float*)d_in[9];
  const float* proj  = (const float*)d_in[10];
  const float* ln2_g = (const float*)d_in[11];
  const float* ln2_b = (const float*)d_in[12];
  const float* ff_w1 = (const float*)d_in[13];
  const float* ff_b1 = (const float*)d_in[14];
  const float* ff_w2 = (const float*)d_in[15];
  const float* ff_b2 = (const float*)d_in[16];
  const float* tgt_w = (const float*)d_in[17];
  const float* tgt_b = (const float*)d_in[18];
  const float* rd_w  = (const float*)d_in[19];
  const float* rd_b  = (const float*)d_in[20];
  float* out = (float*)d_out;

  float* ws = (float*)d_ws;
  // BSD-unit layout:
  // 0 tok | 1 v | 2 q (dead after k_feat) -> Gavg (1179648) + pool (294912)
  // 3 k/attnb | 4-5 h -> kp -> h2 | 6-7 qp -> G (bf16)
  // 8 ckv (2506752, spills 147456 into unit 9; dead after k_attn) / tok2 (after)
  // smalls @ 9*BSD + 147456: diagk, part, gmax, partial
  float* tok   = ws;
  float* v     = ws + (size_t)BSD;
  float* q     = ws + 2 * (size_t)BSD;
  float* Gavg  = ws + 2 * (size_t)BSD;          // 1179648 floats (q dead after k_feat)
  float* pool  = Gavg + 1179648;                // 294912 floats
  float* k     = ws + 3 * (size_t)BSD;
  float* h     = ws + 4 * (size_t)BSD;          // LN1 out; dead after k_qkv
  float* kp    = ws + 4 * (size_t)BSD;          // 2 BSD; written by k_feat after h dead
  float* qp    = ws + 6 * (size_t)BSD;          // 2 BSD; dead after k_attn
  bf16*  G     = (bf16*)(ws + 6 * (size_t)BSD); // 9.4M bf16 (reuses qp)
  float* ckv   = ws + 8 * (size_t)BSD;          // 2506752 floats; dead after k_attn
  float* tok2  = ws + 8 * (size_t)BSD;          // written by k_wo_ln (ckv dead)
  float* attnb = k;                             // k dead after k_feat
  float* h2    = ws + 4 * (size_t)BSD;          // kp dead after k_attn
  float* smalls = ws + 9 * (size_t)BSD + 147456;
  float* diagk = smalls;                        // 147456; k_feat -> k_csfin
  float* part  = diagk + BHS;                   // 2304 used (18432 reserved)
  float* gmax  = part + BHSM / 256;             // 1
  float* partial = gmax + 64;                   // 130

  k_preln<<<dim3(BS / 4), dim3(256), 0, stream>>>(x, pre_w, pre_b, ln1_g, ln1_b, tok, h);
  k_qkv<<<dim3(BS / 32), dim3(256), 0, stream>>>(h, wq, wk, wv, q, k, v);
  k_feat<<<dim3(BHS / 64), dim3(64), 0, stream>>>(q, k, proj, qp, kp, diagk, part);
  k_maxred<<<dim3(1), dim3(256), 0, stream>>>(part, gmax);
  k_csfin<<<dim3(BH * NC), dim3(256), 0, stream>>>(diagk, gmax, v, kp, ckv);
  k_prefix<<<dim3(BH * STATE / 256), dim3(256), 0, stream>>>(ckv);
  k_attn<<<dim3(BH * NC), dim3(64), 0, stream>>>(qp, kp, v, ckv, attnb);
  k_wo_ln<<<dim3(BS / 32), dim3(256), 0, stream>>>(attnb, wo, bo, tok, ln2_g, ln2_b, tok2, h2);
  k_ff1<<<dim3(BS / 64), dim3(256), 0, stream>>>(h2, ff_w1, ff_b1, G);
  k_gavg<<<dim3(B_ * 64 * 36), dim3(256), 0, stream>>>(G, Gavg);
  k_pool2<<<dim3(B_ * 64 * 2), dim3(256), 0, stream>>>(Gavg, tok2, ff_w2, ff_b2, pool);
  k_convsum<<<dim3(B_ * 65), dim3(256), 0, stream>>>(pool, x, tgt_w, partial);
  k_final<<<dim3(B_), dim3(128), 0, stream>>>(partial, tgt_b, rd_w, rd_b, out);
}

// Round 10
// 298.195 us; speedup vs baseline: 1.1245x; 1.1245x over previous
//
#include <hip/hip_runtime.h>
#include <hip/hip_bf16.h>
#include <math.h>

typedef __hip_bfloat16 bf16;
typedef __attribute__((ext_vector_type(8))) short short8;
typedef __attribute__((ext_vector_type(16))) float floatx16;

// Problem constants
constexpr int B_   = 2;
constexpr int T_   = 8;
constexpr int HW   = 48 * 48;          // 2304
constexpr int S_   = T_ * HW;          // 18432
constexpr int D_   = 64;
constexpr int NH   = 4;
constexpr int DH   = 16;
constexpr int M_   = 32;
constexpr int BS   = B_ * S_;          // 36864 tokens
constexpr int BSD  = BS * D_;          // 2359296
constexpr int BH   = B_ * NH;          // 8 sequences
constexpr int BHS  = BH * S_;          // 147456 rows
constexpr int BHSM = BHS * M_;         // 4718592
constexpr int CHUNK = 32;
constexpr int NC   = S_ / CHUNK;       // 576 chunks per sequence
constexpr int STATE = M_ * DH + M_;    // 544 floats of scan state
constexpr float DN = 0.5f;                         // 16^-0.25
constexpr float RATIO = 0.17677669529663687f;      // 32^-0.5

__device__ __forceinline__ unsigned short f2bf(float f) {
  bf16 h = __float2bfloat16(f);
  return *reinterpret_cast<unsigned short*>(&h);
}

// ---------------- fused: 1x1x1 conv3d + softplus + LayerNorm1 ----------------
__global__ void k_preln(const float* __restrict__ x, const float* __restrict__ pw,
                        const float* __restrict__ pb, const float* __restrict__ g,
                        const float* __restrict__ bb,
                        float* __restrict__ tok, float* __restrict__ h) {
  int token = blockIdx.x * 4 + (threadIdx.x >> 6);
  int lane = threadIdx.x & 63;
  int f = token * 64 + lane;          // flat over B*D*S
  int b = f / (D_ * S_);
  int r = f % (D_ * S_);
  int d = r / S_;
  int pos = r % S_;
  const float* xb = x + b * 3 * S_ + pos;
  float a = xb[0] * pw[d * 3 + 0] + xb[S_] * pw[d * 3 + 1] + xb[2 * S_] * pw[d * 3 + 2]
          + pb[d];
  float t = fmaxf(a, 0.f) + log1pf(expf(-fabsf(a)));  // softplus
  tok[f] = t;
  float s1 = t, s2 = t * t;
  for (int off = 32; off; off >>= 1) {
    s1 += __shfl_xor(s1, off);
    s2 += __shfl_xor(s2, off);
  }
  float mu = s1 * (1.f / 64.f);
  float var = s2 * (1.f / 64.f) - mu * mu;
  float rs = rsqrtf(var + 1e-5f);
  h[f] = (t - mu) * rs * g[lane] + bb[lane];
}

// ---------------- QKV projections, register-tiled: q,k,v in [BH][S][16] ----------------
__global__ void __launch_bounds__(256) k_qkv(const float* __restrict__ h,
                      const float* __restrict__ wq, const float* __restrict__ wk,
                      const float* __restrict__ wv,
                      float* __restrict__ q, float* __restrict__ k, float* __restrict__ v) {
  __shared__ __align__(16) float sH[32 * 68];
  int tid = threadIdx.x;
  int tbase = blockIdx.x * 32;
  for (int e = tid; e < 512; e += 256) {
    int row = e >> 4, c4 = e & 15;
    *(float4*)&sH[row * 68 + c4 * 4] = *(const float4*)&h[(tbase + row) * 64 + c4 * 4];
  }
  __syncthreads();
  int tg = tid >> 6;        // 4 groups of 8 tokens
  int cg = tid & 63;        // output col
  float aq[8], ak[8], av[8];
#pragma unroll
  for (int i = 0; i < 8; ++i) { aq[i] = 0.f; ak[i] = 0.f; av[i] = 0.f; }
  for (int dc = 0; dc < 16; ++dc) {
    float4 hf[8];
#pragma unroll
    for (int i = 0; i < 8; ++i) hf[i] = *(const float4*)&sH[(tg * 8 + i) * 68 + dc * 4];
    float wqv[4], wkv[4], wvv[4];
#pragma unroll
    for (int dd = 0; dd < 4; ++dd) {
      int d = dc * 4 + dd;
      wqv[dd] = wq[d * 64 + cg]; wkv[dd] = wk[d * 64 + cg]; wvv[dd] = wv[d * 64 + cg];
    }
#pragma unroll
    for (int i = 0; i < 8; ++i) {
      const float* hp = (const float*)&hf[i];
#pragma unroll
      for (int dd = 0; dd < 4; ++dd) {
        aq[i] += hp[dd] * wqv[dd];
        ak[i] += hp[dd] * wkv[dd];
        av[i] += hp[dd] * wvv[dd];
      }
    }
  }
  int head = cg >> 4, di = cg & 15;
#pragma unroll
  for (int i = 0; i < 8; ++i) {
    int token = tbase + tg * 8 + i;
    int b = token / S_, s = token % S_;
    int o = ((b * NH + head) * S_ + s) * DH + di;
    q[o] = aq[i]; k[o] = ak[i]; v[o] = av[i];
  }
}

// ---------------- feature map, row-per-thread: qp final + raw dash_k + diag_k + block max ----------------
__global__ void __launch_bounds__(64) k_feat(const float* __restrict__ q,
                      const float* __restrict__ k, const float* __restrict__ proj,
                      float* __restrict__ qp, float* __restrict__ kp,
                      float* __restrict__ diagk, float* __restrict__ part) {
  __shared__ __align__(16) float sPT[16 * 32];   // proj^T [d][m]
  int tid = threadIdx.x;
  for (int e = tid; e < 512; e += 64) {
    int d = e >> 5, m = e & 31;
    sPT[d * 32 + m] = proj[m * 16 + d];          // m-fastest write: conflict-free
  }
  __syncthreads();
  int row = blockIdx.x * 64 + tid;
  float qv[16], kv[16];
  float dq = 0.f, dk = 0.f;
  {
    const float4* q4 = (const float4*)(q + (size_t)row * 16);
    const float4* k4 = (const float4*)(k + (size_t)row * 16);
#pragma unroll
    for (int i = 0; i < 4; ++i) {
      float4 t4 = q4[i];
      qv[4*i] = t4.x * DN; qv[4*i+1] = t4.y * DN; qv[4*i+2] = t4.z * DN; qv[4*i+3] = t4.w * DN;
      float4 u4 = k4[i];
      kv[4*i] = u4.x * DN; kv[4*i+1] = u4.y * DN; kv[4*i+2] = u4.z * DN; kv[4*i+3] = u4.w * DN;
    }
#pragma unroll
    for (int d = 0; d < 16; ++d) { dq += qv[d] * qv[d]; dk += kv[d] * kv[d]; }
    dq *= 0.5f; dk *= 0.5f;
  }
  float accq[32], acck[32];
#pragma unroll
  for (int m = 0; m < 32; ++m) { accq[m] = 0.f; acck[m] = 0.f; }
#pragma unroll
  for (int d = 0; d < 16; ++d) {
    float qd = qv[d], kd = kv[d];
    const float4* pr = (const float4*)&sPT[d * 32];
#pragma unroll
    for (int m4 = 0; m4 < 8; ++m4) {
      float4 p = pr[m4];                          // wave-uniform address: broadcast
      accq[4*m4+0] += qd * p.x; accq[4*m4+1] += qd * p.y;
      accq[4*m4+2] += qd * p.z; accq[4*m4+3] += qd * p.w;
      acck[4*m4+0] += kd * p.x; acck[4*m4+1] += kd * p.y;
      acck[4*m4+2] += kd * p.z; acck[4*m4+3] += kd * p.w;
    }
  }
  float mx = accq[0];
#pragma unroll
  for (int m = 1; m < 32; ++m) mx = fmaxf(mx, accq[m]);
#pragma unroll
  for (int m4 = 0; m4 < 8; ++m4) {
    float4 o;
    o.x = RATIO * (expf(accq[4*m4+0] - dq - mx) + 1e-4f);
    o.y = RATIO * (expf(accq[4*m4+1] - dq - mx) + 1e-4f);
    o.z = RATIO * (expf(accq[4*m4+2] - dq - mx) + 1e-4f);
    o.w = RATIO * (expf(accq[4*m4+3] - dq - mx) + 1e-4f);
    *(float4*)&qp[(size_t)row * 32 + m4 * 4] = o;
  }
  float bmax = acck[0];
#pragma unroll
  for (int m = 1; m < 32; ++m) bmax = fmaxf(bmax, acck[m]);
#pragma unroll
  for (int m4 = 0; m4 < 8; ++m4)
    *(float4*)&kp[(size_t)row * 32 + m4 * 4] = *(float4*)&acck[4 * m4];
  diagk[row] = dk;
  for (int off = 32; off; off >>= 1) bmax = fmaxf(bmax, __shfl_xor(bmax, off));
  if (tid == 0) part[blockIdx.x] = bmax;
}

__global__ void k_maxred(const float* __restrict__ part, float* __restrict__ gmax) {
  float m = -3.4e38f;
  for (int i = threadIdx.x; i < BHS / 64; i += 256) m = fmaxf(m, part[i]);
  __shared__ float red[256];
  red[threadIdx.x] = m;
  __syncthreads();
  for (int s = 128; s; s >>= 1) {
    if (threadIdx.x < s) red[threadIdx.x] = fmaxf(red[threadIdx.x], red[threadIdx.x + s]);
    __syncthreads();
  }
  if (!threadIdx.x) gmax[0] = red[0];
}

// ---------------- kp-finalize + per-chunk sums; accumulation from L1-hot global ----------------
__global__ void __launch_bounds__(256) k_csfin(const float* __restrict__ diagk,
                      const float* __restrict__ gmax, const float* __restrict__ v,
                      float* __restrict__ kp, float* __restrict__ ckv) {
  int blk = blockIdx.x;
  int bh = blk / NC, c = blk % NC;
  int tid = threadIdx.x;
  int base = bh * S_ + c * CHUNK;
  float gm = gmax[0];
  {
    int row = tid >> 3, m4 = tid & 7;            // 32 rows x 8 float4
    float4 dash = *(const float4*)&kp[(size_t)(base + row) * 32 + m4 * 4];
    float dg = diagk[base + row] + gm;
    float4 fin;
    fin.x = RATIO * (expf(dash.x - dg) + 1e-4f);
    fin.y = RATIO * (expf(dash.y - dg) + 1e-4f);
    fin.z = RATIO * (expf(dash.z - dg) + 1e-4f);
    fin.w = RATIO * (expf(dash.w - dg) + 1e-4f);
    *(float4*)&kp[(size_t)(base + row) * 32 + m4 * 4] = fin;
  }
  __syncthreads();   // block-level global visibility
  int m0 = tid >> 4, d0 = tid & 15;
  int m1 = m0 + 16;
  float a0 = 0.f, a1 = 0.f, az0 = 0.f, az1 = 0.f;
  for (int t = 0; t < CHUNK; ++t) {
    const float* kr = kp + (size_t)(base + t) * 32;
    float k0 = kr[m0];
    float k1 = kr[m1];
    float vv = v[(size_t)(base + t) * 16 + d0];
    a0 += k0 * vv;
    a1 += k1 * vv;
    if (d0 == 0) { az0 += k0; az1 += k1; }
  }
  float* outp = ckv + (size_t)blk * STATE;
  outp[m0 * 16 + d0] = a0;
  outp[m1 * 16 + d0] = a1;
  if (d0 == 0) { outp[512 + m0] = az0; outp[512 + m1] = az1; }
}

// ---------------- exclusive prefix over chunks (in place), one scan-column per thread ----------------
__global__ void k_prefix(float* __restrict__ ckv) {
  int idx = blockIdx.x * 256 + threadIdx.x;      // 17 blocks x 256 = 4352 = BH*544
  int bh = idx / STATE, c = idx % STATE;
  float run = 0.f;
  for (int j0 = 0; j0 < NC; j0 += 16) {
    float tb[16];
#pragma unroll
    for (int jj = 0; jj < 16; ++jj) tb[jj] = ckv[((size_t)bh * NC + j0 + jj) * STATE + c];
#pragma unroll
    for (int jj = 0; jj < 16; ++jj) {
      ckv[((size_t)bh * NC + j0 + jj) * STATE + c] = run;
      run += tb[jj];
    }
  }
}

// ---------------- within-chunk causal attention via MFMA (CHUNK=32; 4 chunks/block, 1 wave each) ----
// P = Qp Kp^T (2x mfma_32x32x16_bf16), causal-mask in C-layout, LDS round-trip to A-layout,
// O = P[V|1] + Qp[S|z]  -> col 16 of the accumulator is the denominator.
__global__ void __launch_bounds__(256) k_attn(const float* __restrict__ qp,
                                              const float* __restrict__ kp,
                                              const float* __restrict__ v,
                                              const float* __restrict__ ckv,
                                              float* __restrict__ attn) {
  __shared__ __align__(16) float sP[4][32 * 33 + 4];
  int tid = threadIdx.x;
  int w = tid >> 6;                 // wave -> chunk
  int L = tid & 63;
  int half = L >> 5;
  int n = L & 31;
  int chunk = blockIdx.x * 4 + w;
  int bh = chunk / NC, c = chunk % NC;
  int base = bh * S_ + c * CHUNK;

  // A-frags of Qp (A[i=n][k=half*8+j]) and B-frags of Kp (B[k][t=n]=kp[t][half*8+j])
  const float* qrow = qp + (size_t)(base + n) * 32 + half * 8;
  const float* krow = kp + (size_t)(base + n) * 32 + half * 8;
  short8 a1, a2, b1, b2;
  {
    float4 q0 = *(const float4*)&qrow[0];
    float4 q1 = *(const float4*)&qrow[4];
    float4 q2 = *(const float4*)&qrow[16];
    float4 q3 = *(const float4*)&qrow[20];
    float4 k0 = *(const float4*)&krow[0];
    float4 k1 = *(const float4*)&krow[4];
    float4 k2 = *(const float4*)&krow[16];
    float4 k3 = *(const float4*)&krow[20];
    a1[0]=(short)f2bf(q0.x); a1[1]=(short)f2bf(q0.y); a1[2]=(short)f2bf(q0.z); a1[3]=(short)f2bf(q0.w);
    a1[4]=(short)f2bf(q1.x); a1[5]=(short)f2bf(q1.y); a1[6]=(short)f2bf(q1.z); a1[7]=(short)f2bf(q1.w);
    a2[0]=(short)f2bf(q2.x); a2[1]=(short)f2bf(q2.y); a2[2]=(short)f2bf(q2.z); a2[3]=(short)f2bf(q2.w);
    a2[4]=(short)f2bf(q3.x); a2[5]=(short)f2bf(q3.y); a2[6]=(short)f2bf(q3.z); a2[7]=(short)f2bf(q3.w);
    b1[0]=(short)f2bf(k0.x); b1[1]=(short)f2bf(k0.y); b1[2]=(short)f2bf(k0.z); b1[3]=(short)f2bf(k0.w);
    b1[4]=(short)f2bf(k1.x); b1[5]=(short)f2bf(k1.y); b1[6]=(short)f2bf(k1.z); b1[7]=(short)f2bf(k1.w);
    b2[0]=(short)f2bf(k2.x); b2[1]=(short)f2bf(k2.y); b2[2]=(short)f2bf(k2.z); b2[3]=(short)f2bf(k2.w);
    b2[4]=(short)f2bf(k3.x); b2[5]=(short)f2bf(k3.y); b2[6]=(short)f2bf(k3.z); b2[7]=(short)f2bf(k3.w);
  }
  floatx16 P;
#pragma unroll
  for (int i = 0; i < 16; ++i) P[i] = 0.f;
  P = __builtin_amdgcn_mfma_f32_32x32x16_bf16(a1, b1, P, 0, 0, 0);
  P = __builtin_amdgcn_mfma_f32_32x32x16_bf16(a2, b2, P, 0, 0, 0);

  // causal mask (keep t<=i) and LDS round-trip to A-layout
  float* sp = &sP[w][0];
#pragma unroll
  for (int r = 0; r < 16; ++r) {
    int i = (r & 3) + 8 * (r >> 2) + 4 * half;
    sp[i * 33 + n] = (n <= i) ? P[r] : 0.f;
  }
  __syncthreads();
  short8 pa1, pa2;
#pragma unroll
  for (int j = 0; j < 8; ++j) {
    pa1[j] = (short)f2bf(sp[n * 33 + half * 8 + j]);
    pa2[j] = (short)f2bf(sp[n * 33 + 16 + half * 8 + j]);
  }

  // B-frags: V with ones-column (col 16), state S with z-column (col 16)
  const float* cs = ckv + (size_t)chunk * STATE;
  short8 vb1, vb2, sb1, sb2;
#pragma unroll
  for (int j = 0; j < 8; ++j) {
    int t1 = half * 8 + j, t2 = 16 + half * 8 + j;
    float x1 = (n < 16) ? v[(size_t)(base + t1) * 16 + n] : (n == 16 ? 1.f : 0.f);
    float x2 = (n < 16) ? v[(size_t)(base + t2) * 16 + n] : (n == 16 ? 1.f : 0.f);
    vb1[j] = (short)f2bf(x1);
    vb2[j] = (short)f2bf(x2);
    float y1 = (n < 16) ? cs[t1 * 16 + n] : (n == 16 ? cs[512 + t1] : 0.f);
    float y2 = (n < 16) ? cs[t2 * 16 + n] : (n == 16 ? cs[512 + t2] : 0.f);
    sb1[j] = (short)f2bf(y1);
    sb2[j] = (short)f2bf(y2);
  }

  floatx16 O;
#pragma unroll
  for (int i = 0; i < 16; ++i) O[i] = 0.f;
  O = __builtin_amdgcn_mfma_f32_32x32x16_bf16(pa1, vb1, O, 0, 0, 0);
  O = __builtin_amdgcn_mfma_f32_32x32x16_bf16(pa2, vb2, O, 0, 0, 0);
  O = __builtin_amdgcn_mfma_f32_32x32x16_bf16(a1, sb1, O, 0, 0, 0);
  O = __builtin_amdgcn_mfma_f32_32x32x16_bf16(a2, sb2, O, 0, 0, 0);

  // den lives in column 16 (lanes 16 / 48); divide and store cols 0..15
  int srcl = 16 + 32 * half;
  float res[16];
#pragma unroll
  for (int r = 0; r < 16; ++r) {
    float den = __shfl(O[r], srcl, 64);
    res[r] = O[r] / den;
  }
  if (n < 16) {
    int b = bh >> 2, head = bh & 3;
#pragma unroll
    for (int r = 0; r < 16; ++r) {
      int i = (r & 3) + 8 * (r >> 2) + 4 * half;
      attn[((size_t)(b * S_ + c * CHUNK + i)) * 64 + head * 16 + n] = res[r];
    }
  }
}

// ---------------- attn @ wo + bo + residual + LayerNorm2, fused ----------------
__global__ void __launch_bounds__(256) k_wo_ln(const float* __restrict__ attn,
                        const float* __restrict__ wo, const float* __restrict__ bo,
                        const float* __restrict__ tok, const float* __restrict__ g,
                        const float* __restrict__ bb,
                        float* __restrict__ tok2, float* __restrict__ h2) {
  __shared__ __align__(16) float sA[32 * 68];
  int tid = threadIdx.x;
  int tbase = blockIdx.x * 32;
  for (int e = tid; e < 512; e += 256) {
    int row = e >> 4, c4 = e & 15;
    *(float4*)&sA[row * 68 + c4 * 4] = *(const float4*)&attn[(tbase + row) * 64 + c4 * 4];
  }
  __syncthreads();
  int tg = tid >> 5;
  int cg = tid & 31;
  int c0 = cg * 2, c1 = c0 + 1;
  float a0[4], a1[4];
#pragma unroll
  for (int i = 0; i < 4; ++i) { a0[i] = 0.f; a1[i] = 0.f; }
  for (int dc = 0; dc < 16; ++dc) {
    float4 af[4];
#pragma unroll
    for (int i = 0; i < 4; ++i) af[i] = *(const float4*)&sA[(tg * 4 + i) * 68 + dc * 4];
    float w0[4], w1v[4];
#pragma unroll
    for (int dd = 0; dd < 4; ++dd) {
      int d = dc * 4 + dd;
      w0[dd] = wo[d * 64 + c0]; w1v[dd] = wo[d * 64 + c1];
    }
#pragma unroll
    for (int i = 0; i < 4; ++i) {
      const float* ap = (const float*)&af[i];
#pragma unroll
      for (int dd = 0; dd < 4; ++dd) { a0[i] += ap[dd] * w0[dd]; a1[i] += ap[dd] * w1v[dd]; }
    }
  }
  float bo0 = bo[c0], bo1 = bo[c1];
  float g0 = g[c0], g1 = g[c1], be0 = bb[c0], be1 = bb[c1];
#pragma unroll
  for (int i = 0; i < 4; ++i) {
    int token = tbase + tg * 4 + i;
    float t0 = tok[token * 64 + c0] + a0[i] + bo0;
    float t1 = tok[token * 64 + c1] + a1[i] + bo1;
    float s1 = t0 + t1, s2 = t0 * t0 + t1 * t1;
    for (int off = 16; off; off >>= 1) {
      s1 += __shfl_xor(s1, off, 32);
      s2 += __shfl_xor(s2, off, 32);
    }
    float mu = s1 * (1.f / 64.f);
    float var = s2 * (1.f / 64.f) - mu * mu;
    float rs = rsqrtf(var + 1e-5f);
    tok2[token * 64 + c0] = t0;
    tok2[token * 64 + c1] = t1;
    h2[token * 64 + c0] = (t0 - mu) * rs * g0 + be0;
    h2[token * 64 + c1] = (t1 - mu) * rs * g1 + be1;
  }
}

// ---------------- FF phase 1: G = gelu(h2 @ W1 + b1), bf16 out ----------------
__global__ void __launch_bounds__(256) k_ff1(const float* __restrict__ h2,
                                             const float* __restrict__ w1,
                                             const float* __restrict__ b1,
                                             bf16* __restrict__ G) {
  __shared__ __align__(16) float sH[64 * 68];   // 17.4 KB
  int tid = threadIdx.x;
  int tbase = blockIdx.x * 64;
  for (int e = tid; e < 1024; e += 256) {
    int row = e >> 4, c4 = e & 15;
    *(float4*)&sH[row * 68 + c4 * 4] = *(const float4*)&h2[(size_t)(tbase + row) * 64 + c4 * 4];
  }
  __syncthreads();
  int tg = tid >> 5;        // 8 groups of 8 tokens
  int cg = tid & 31;        // 8 cols each: cg*8..+7
  float acc[8][8];
#pragma unroll
  for (int i = 0; i < 8; ++i)
#pragma unroll
    for (int j = 0; j < 8; ++j) acc[i][j] = 0.f;
  for (int dc = 0; dc < 16; ++dc) {
    float4 hf[8];
#pragma unroll
    for (int i = 0; i < 8; ++i) hf[i] = *(const float4*)&sH[(tg * 8 + i) * 68 + dc * 4];
    float4 wa[4], wb[4];
#pragma unroll
    for (int dd = 0; dd < 4; ++dd) {
      int d = dc * 4 + dd;
      wa[dd] = *(const float4*)&w1[d * 256 + cg * 8];
      wb[dd] = *(const float4*)&w1[d * 256 + cg * 8 + 4];
    }
#pragma unroll
    for (int i = 0; i < 8; ++i) {
      const float* hp = (const float*)&hf[i];
#pragma unroll
      for (int dd = 0; dd < 4; ++dd) {
        float hv = hp[dd];
        const float* pa = (const float*)&wa[dd];
        const float* pb = (const float*)&wb[dd];
        acc[i][0] += hv * pa[0]; acc[i][1] += hv * pa[1];
        acc[i][2] += hv * pa[2]; acc[i][3] += hv * pa[3];
        acc[i][4] += hv * pb[0]; acc[i][5] += hv * pb[1];
        acc[i][6] += hv * pb[2]; acc[i][7] += hv * pb[3];
      }
    }
  }
  float bv[8];
  *(float4*)&bv[0] = *(const float4*)&b1[cg * 8];
  *(float4*)&bv[4] = *(const float4*)&b1[cg * 8 + 4];
#pragma unroll
  for (int i = 0; i < 8; ++i) {
    unsigned int pk[4];
#pragma unroll
    for (int j = 0; j < 4; ++j) {
      float x0 = acc[i][2 * j] + bv[2 * j];
      float x1 = acc[i][2 * j + 1] + bv[2 * j + 1];
      float g0 = 0.5f * x0 * (1.f + erff(x0 * 0.70710678118654752f));
      float g1 = 0.5f * x1 * (1.f + erff(x1 * 0.70710678118654752f));
      pk[j] = (unsigned int)f2bf(g0) | ((unsigned int)f2bf(g1) << 16);
    }
    int token = tbase + tg * 8 + i;
    *(uint4*)&G[(size_t)token * 256 + cg * 8] = *(uint4*)&pk[0];
  }
}

// ---------------- Gavg: mean over T of the 8 G rows feeding each pool element ----------------
__global__ void k_gavg(const bf16* __restrict__ G, float* __restrict__ Gavg) {
  int blk = blockIdx.x;                 // 4608 = B*64*36
  int tid = threadIdx.x;                // column 0..255
  int b = blk / 2304;
  int rem = blk % 2304;
  int ch = rem / 36, jp = rem % 36;
  size_t gbase = ((size_t)b * 18432 + ch * 288 + jp) * 256 + tid;
  float s = 0.f;
#pragma unroll
  for (int t = 0; t < 8; ++t) s += __bfloat162float(G[gbase + (size_t)t * 36 * 256]);
  Gavg[(size_t)blk * 256 + tid] = s * 0.125f;
}

// ---------------- pool = mean_t(tok2) + Gavg @ W2 + b2 (FF2 folded 8x by linearity) ----------------
__global__ void __launch_bounds__(256) k_pool2(const float* __restrict__ Gavg,
                        const float* __restrict__ tok2, const float* __restrict__ w2,
                        const float* __restrict__ b2, float* __restrict__ pool) {
  __shared__ __align__(16) float sG[18 * 256];     // 18.4 KB
  __shared__ __align__(16) float sRed[4 * 18 * 64]; // 18.4 KB
  int blk = blockIdx.x;
  int b = blk / 128;
  int rem = blk % 128;
  int ch = rem >> 1, jph = rem & 1;
  int tid = threadIdx.x;
  size_t grow0 = ((size_t)(b * 64 + ch) * 36 + jph * 18) * 256;
  for (int e = tid; e < 1152; e += 256) {          // 18 rows x 64 float4
    int row = e >> 6, c4 = e & 63;
    *(float4*)&sG[row * 256 + c4 * 4] = *(const float4*)&Gavg[grow0 + row * 256 + c4 * 4];
  }
  __syncthreads();
  int kg = tid >> 6, dd = tid & 63;
  float acc[18];
#pragma unroll
  for (int i = 0; i < 18; ++i) acc[i] = 0.f;
  for (int k4 = 0; k4 < 16; ++k4) {
    int k = kg * 64 + k4 * 4;
    float w0 = w2[(k + 0) * 64 + dd];
    float w1 = w2[(k + 1) * 64 + dd];
    float w2v = w2[(k + 2) * 64 + dd];
    float w3 = w2[(k + 3) * 64 + dd];
#pragma unroll
    for (int i = 0; i < 18; ++i) {
      float4 gf = *(const float4*)&sG[i * 256 + k];   // wave-wide broadcast
      acc[i] += gf.x * w0 + gf.y * w1 + gf.z * w2v + gf.w * w3;
    }
  }
#pragma unroll
  for (int i = 0; i < 18; ++i) sRed[(kg * 18 + i) * 64 + dd] = acc[i];
  __syncthreads();
  for (int o = tid; o < 1152; o += 256) {
    int jp18 = o >> 6, d2 = o & 63;
    float gsum = sRed[(0 * 18 + jp18) * 64 + d2] + sRed[(1 * 18 + jp18) * 64 + d2]
               + sRed[(2 * 18 + jp18) * 64 + d2] + sRed[(3 * 18 + jp18) * 64 + d2];
    int p = (jph * 18 + jp18) * 64 + d2;
    size_t tbase = (size_t)b * 1179648 + (size_t)ch * 18432 + p;
    float ts = 0.f;
#pragma unroll
    for (int t = 0; t < 8; ++t) ts += tok2[tbase + t * 2304];
    pool[((size_t)(b * 64 + ch)) * HW + p] = ts * 0.125f + gsum + b2[d2];
  }
}

// ---------------- conv(5x5,pad2) + global-avg-pool folded ----------------
__global__ void __launch_bounds__(256) k_convsum(const float* __restrict__ pool,
                                                 const float* __restrict__ x,
                                                 const float* __restrict__ w,
                                                 float* __restrict__ partial) {
  int blk = blockIdx.x;          // b*65 + ch
  int b = blk / 65, ch = blk % 65;
  int tid = threadIdx.x;
  __shared__ float cls[25];
  __shared__ float red[256];
  if (tid < 25) {
    int ry = tid / 5, rx = tid % 5;
    int kh0 = (ry <= 2) ? 0 : (ry == 3 ? 1 : 2);
    int kh1 = (ry >= 2) ? 4 : (ry == 1 ? 3 : 2);
    int kw0 = (rx <= 2) ? 0 : (rx == 3 ? 1 : 2);
    int kw1 = (rx >= 2) ? 4 : (rx == 1 ? 3 : 2);
    float s = 0.f;
    for (int kh = kh0; kh <= kh1; ++kh)
      for (int kw = kw0; kw <= kw1; ++kw)
        s += w[ch * 25 + kh * 5 + kw];
    cls[tid] = s;
  }
  __syncthreads();
  const float* pc = (ch < 64) ? (pool + ((size_t)(b * 64 + ch)) * HW)
                              : (x + (size_t)b * 3 * S_ + 2 * S_);
  float acc = 0.f;
#pragma unroll
  for (int e = tid; e < HW; e += 256) {
    int iy = e / 48, ix = e % 48;
    int ry = (iy == 0) ? 0 : (iy == 1) ? 1 : (iy <= 45) ? 2 : (iy == 46) ? 3 : 4;
    int rx = (ix == 0) ? 0 : (ix == 1) ? 1 : (ix <= 45) ? 2 : (ix == 46) ? 3 : 4;
    acc += pc[e] * cls[ry * 5 + rx];
  }
  red[tid] = acc;
  __syncthreads();
  for (int s = 128; s; s >>= 1) {
    if (tid < s) red[tid] += red[tid + s];
    __syncthreads();
  }
  if (!tid) partial[blk] = red[0];
}

// ---------------- reduce 65 channel sums per b + readout ----------------
__global__ void k_final(const float* __restrict__ partial, const float* __restrict__ tgt_b,
                        const float* __restrict__ rd_w, const float* __restrict__ rd_b,
                        float* __restrict__ out) {
  int b = blockIdx.x;
  int lane = threadIdx.x;
  float s = (lane < 65) ? partial[b * 65 + lane] : 0.f;
  for (int off = 32; off; off >>= 1) s += __shfl_down(s, off, 64);
  __shared__ float r2;
  if (lane == 64) r2 = s;
  __syncthreads();
  if (!lane) {
    float tot = s + r2;
    float mean = tot / 2304.f + tgt_b[0];
    out[b] = mean * rd_w[0] + rd_b[0];
  }
}

extern "C" void kernel_launch(void* const* d_in, const int* in_sizes, int n_in,
                              void* d_out, int out_size, void* d_ws, size_t ws_size,
                              hipStream_t stream) {
  const float* x     = (const float*)d_in[0];
  const float* pre_w = (const float*)d_in[1];
  const float* pre_b = (const float*)d_in[2];
  const float* ln1_g = (const float*)d_in[3];
  const float* ln1_b = (const float*)d_in[4];
  const float* wq    = (const float*)d_in[5];
  const float* wk    = (const float*)d_in[6];
  const float* wv    = (const float*)d_in[7];
  const float* wo    = (const float*)d_in[8];
  const float* bo    = (const float*)d_in[9];
  const float* proj  = (const float*)d_in[10];
  const float* ln2_g = (const float*)d_in[11];
  const float* ln2_b = (const float*)d_in[12];
  const float* ff_w1 = (const float*)d_in[13];
  const float* ff_b1 = (const float*)d_in[14];
  const float* ff_w2 = (const float*)d_in[15];
  const float* ff_b2 = (const float*)d_in[16];
  const float* tgt_w = (const float*)d_in[17];
  const float* tgt_b = (const float*)d_in[18];
  const float* rd_w  = (const float*)d_in[19];
  const float* rd_b  = (const float*)d_in[20];
  float* out = (float*)d_out;

  float* ws = (float*)d_ws;
  float* tok   = ws;
  float* v     = ws + (size_t)BSD;
  float* q     = ws + 2 * (size_t)BSD;
  float* Gavg  = ws + 2 * (size_t)BSD;          // q dead after k_feat
  float* pool  = Gavg + 1179648;                // 294912 floats
  float* k     = ws + 3 * (size_t)BSD;
  float* h     = ws + 4 * (size_t)BSD;          // LN1 out; dead after k_qkv
  float* kp    = ws + 4 * (size_t)BSD;          // 2 BSD; written by k_feat after h dead
  float* qp    = ws + 6 * (size_t)BSD;          // 2 BSD; dead after k_attn
  bf16*  G     = (bf16*)(ws + 6 * (size_t)BSD); // 9.4M bf16 (reuses qp)
  float* ckv   = ws + 8 * (size_t)BSD;          // 2506752 floats; dead after k_attn
  float* tok2  = ws + 8 * (size_t)BSD;          // written by k_wo_ln (ckv dead)
  float* attnb = k;                             // k dead after k_feat
  float* h2    = ws + 4 * (size_t)BSD;          // kp dead after k_attn
  float* smalls = ws + 9 * (size_t)BSD + 147456;
  float* diagk = smalls;                        // 147456; k_feat -> k_csfin
  float* part  = diagk + BHS;                   // 2304 used
  float* gmax  = part + BHSM / 256;             // 1
  float* partial = gmax + 64;                   // 130

  k_preln<<<dim3(BS / 4), dim3(256), 0, stream>>>(x, pre_w, pre_b, ln1_g, ln1_b, tok, h);
  k_qkv<<<dim3(BS / 32), dim3(256), 0, stream>>>(h, wq, wk, wv, q, k, v);
  k_feat<<<dim3(BHS / 64), dim3(64), 0, stream>>>(q, k, proj, qp, kp, diagk, part);
  k_maxred<<<dim3(1), dim3(256), 0, stream>>>(part, gmax);
  k_csfin<<<dim3(BH * NC), dim3(256), 0, stream>>>(diagk, gmax, v, kp, ckv);
  k_prefix<<<dim3(BH * STATE / 256), dim3(256), 0, stream>>>(ckv);
  k_attn<<<dim3(BH * NC / 4), dim3(256), 0, stream>>>(qp, kp, v, ckv, attnb);
  k_wo_ln<<<dim3(BS / 32), dim3(256), 0, stream>>>(attnb, wo, bo, tok, ln2_g, ln2_b, tok2, h2);
  k_ff1<<<dim3(BS / 64), dim3(256), 0, stream>>>(h2, ff_w1, ff_b1, G);
  k_gavg<<<dim3(B_ * 64 * 36), dim3(256), 0, stream>>>(G, Gavg);
  k_pool2<<<dim3(B_ * 64 * 2), dim3(256), 0, stream>>>(Gavg, tok2, ff_w2, ff_b2, pool);
  k_convsum<<<dim3(B_ * 65), dim3(256), 0, stream>>>(pool, x, tgt_w, partial);
  k_final<<<dim3(B_), dim3(128), 0, stream>>>(partial, tgt_b, rd_w, rd_b, out);
}

// Round 11
// 281.539 us; speedup vs baseline: 1.1911x; 1.0592x over previous
//
#include <hip/hip_runtime.h>
#include <hip/hip_bf16.h>
#include <math.h>

typedef __hip_bfloat16 bf16;
typedef __attribute__((ext_vector_type(8))) short short8;
typedef __attribute__((ext_vector_type(16))) float floatx16;

// Problem constants
constexpr int B_   = 2;
constexpr int T_   = 8;
constexpr int HW   = 48 * 48;          // 2304
constexpr int S_   = T_ * HW;          // 18432
constexpr int D_   = 64;
constexpr int NH   = 4;
constexpr int DH   = 16;
constexpr int M_   = 32;
constexpr int BS   = B_ * S_;          // 36864 tokens
constexpr int BSD  = BS * D_;          // 2359296
constexpr int BH   = B_ * NH;          // 8 sequences
constexpr int BHS  = BH * S_;          // 147456 rows
constexpr int BHSM = BHS * M_;         // 4718592
constexpr int CHUNK = 32;
constexpr int NC   = S_ / CHUNK;       // 576 chunks per sequence
constexpr int STATE = M_ * DH + M_;    // 544 floats of scan state
constexpr float DN = 0.5f;                         // 16^-0.25
constexpr float RATIO = 0.17677669529663687f;      // 32^-0.5

__device__ __forceinline__ unsigned short f2bf(float f) {
  bf16 h = __float2bfloat16(f);
  return *reinterpret_cast<unsigned short*>(&h);
}

// ---------------- fused: 1x1x1 conv3d + softplus + LayerNorm1 ----------------
__global__ void k_preln(const float* __restrict__ x, const float* __restrict__ pw,
                        const float* __restrict__ pb, const float* __restrict__ g,
                        const float* __restrict__ bb,
                        float* __restrict__ tok, float* __restrict__ h) {
  int token = blockIdx.x * 4 + (threadIdx.x >> 6);
  int lane = threadIdx.x & 63;
  int f = token * 64 + lane;          // flat over B*D*S
  int b = f / (D_ * S_);
  int r = f % (D_ * S_);
  int d = r / S_;
  int pos = r % S_;
  const float* xb = x + b * 3 * S_ + pos;
  float a = xb[0] * pw[d * 3 + 0] + xb[S_] * pw[d * 3 + 1] + xb[2 * S_] * pw[d * 3 + 2]
          + pb[d];
  float t = fmaxf(a, 0.f) + log1pf(expf(-fabsf(a)));  // softplus
  tok[f] = t;
  float s1 = t, s2 = t * t;
  for (int off = 32; off; off >>= 1) {
    s1 += __shfl_xor(s1, off);
    s2 += __shfl_xor(s2, off);
  }
  float mu = s1 * (1.f / 64.f);
  float var = s2 * (1.f / 64.f) - mu * mu;
  float rs = rsqrtf(var + 1e-5f);
  h[f] = (t - mu) * rs * g[lane] + bb[lane];
}

// ---------------- QKV projections, register-tiled: q,k,v in [BH][S][16] ----------------
__global__ void __launch_bounds__(256) k_qkv(const float* __restrict__ h,
                      const float* __restrict__ wq, const float* __restrict__ wk,
                      const float* __restrict__ wv,
                      float* __restrict__ q, float* __restrict__ k, float* __restrict__ v) {
  __shared__ __align__(16) float sH[32 * 68];
  int tid = threadIdx.x;
  int tbase = blockIdx.x * 32;
  for (int e = tid; e < 512; e += 256) {
    int row = e >> 4, c4 = e & 15;
    *(float4*)&sH[row * 68 + c4 * 4] = *(const float4*)&h[(tbase + row) * 64 + c4 * 4];
  }
  __syncthreads();
  int tg = tid >> 6;        // 4 groups of 8 tokens
  int cg = tid & 63;        // output col
  float aq[8], ak[8], av[8];
#pragma unroll
  for (int i = 0; i < 8; ++i) { aq[i] = 0.f; ak[i] = 0.f; av[i] = 0.f; }
  for (int dc = 0; dc < 16; ++dc) {
    float4 hf[8];
#pragma unroll
    for (int i = 0; i < 8; ++i) hf[i] = *(const float4*)&sH[(tg * 8 + i) * 68 + dc * 4];
    float wqv[4], wkv[4], wvv[4];
#pragma unroll
    for (int dd = 0; dd < 4; ++dd) {
      int d = dc * 4 + dd;
      wqv[dd] = wq[d * 64 + cg]; wkv[dd] = wk[d * 64 + cg]; wvv[dd] = wv[d * 64 + cg];
    }
#pragma unroll
    for (int i = 0; i < 8; ++i) {
      const float* hp = (const float*)&hf[i];
#pragma unroll
      for (int dd = 0; dd < 4; ++dd) {
        aq[i] += hp[dd] * wqv[dd];
        ak[i] += hp[dd] * wkv[dd];
        av[i] += hp[dd] * wvv[dd];
      }
    }
  }
  int head = cg >> 4, di = cg & 15;
#pragma unroll
  for (int i = 0; i < 8; ++i) {
    int token = tbase + tg * 8 + i;
    int b = token / S_, s = token % S_;
    int o = ((b * NH + head) * S_ + s) * DH + di;
    q[o] = aq[i]; k[o] = ak[i]; v[o] = av[i];
  }
}

// ---------------- feature map, row-per-thread: qp final + raw dash_k + diag_k + block max ----------------
__global__ void __launch_bounds__(64) k_feat(const float* __restrict__ q,
                      const float* __restrict__ k, const float* __restrict__ proj,
                      float* __restrict__ qp, float* __restrict__ kp,
                      float* __restrict__ diagk, float* __restrict__ part) {
  __shared__ __align__(16) float sPT[16 * 32];   // proj^T [d][m]
  int tid = threadIdx.x;
  for (int e = tid; e < 512; e += 64) {
    int d = e >> 5, m = e & 31;
    sPT[d * 32 + m] = proj[m * 16 + d];          // m-fastest write: conflict-free
  }
  __syncthreads();
  int row = blockIdx.x * 64 + tid;
  float qv[16], kv[16];
  float dq = 0.f, dk = 0.f;
  {
    const float4* q4 = (const float4*)(q + (size_t)row * 16);
    const float4* k4 = (const float4*)(k + (size_t)row * 16);
#pragma unroll
    for (int i = 0; i < 4; ++i) {
      float4 t4 = q4[i];
      qv[4*i] = t4.x * DN; qv[4*i+1] = t4.y * DN; qv[4*i+2] = t4.z * DN; qv[4*i+3] = t4.w * DN;
      float4 u4 = k4[i];
      kv[4*i] = u4.x * DN; kv[4*i+1] = u4.y * DN; kv[4*i+2] = u4.z * DN; kv[4*i+3] = u4.w * DN;
    }
#pragma unroll
    for (int d = 0; d < 16; ++d) { dq += qv[d] * qv[d]; dk += kv[d] * kv[d]; }
    dq *= 0.5f; dk *= 0.5f;
  }
  float accq[32], acck[32];
#pragma unroll
  for (int m = 0; m < 32; ++m) { accq[m] = 0.f; acck[m] = 0.f; }
#pragma unroll
  for (int d = 0; d < 16; ++d) {
    float qd = qv[d], kd = kv[d];
    const float4* pr = (const float4*)&sPT[d * 32];
#pragma unroll
    for (int m4 = 0; m4 < 8; ++m4) {
      float4 p = pr[m4];                          // wave-uniform address: broadcast
      accq[4*m4+0] += qd * p.x; accq[4*m4+1] += qd * p.y;
      accq[4*m4+2] += qd * p.z; accq[4*m4+3] += qd * p.w;
      acck[4*m4+0] += kd * p.x; acck[4*m4+1] += kd * p.y;
      acck[4*m4+2] += kd * p.z; acck[4*m4+3] += kd * p.w;
    }
  }
  float mx = accq[0];
#pragma unroll
  for (int m = 1; m < 32; ++m) mx = fmaxf(mx, accq[m]);
#pragma unroll
  for (int m4 = 0; m4 < 8; ++m4) {
    float4 o;
    o.x = RATIO * (expf(accq[4*m4+0] - dq - mx) + 1e-4f);
    o.y = RATIO * (expf(accq[4*m4+1] - dq - mx) + 1e-4f);
    o.z = RATIO * (expf(accq[4*m4+2] - dq - mx) + 1e-4f);
    o.w = RATIO * (expf(accq[4*m4+3] - dq - mx) + 1e-4f);
    *(float4*)&qp[(size_t)row * 32 + m4 * 4] = o;
  }
  float bmax = acck[0];
#pragma unroll
  for (int m = 1; m < 32; ++m) bmax = fmaxf(bmax, acck[m]);
#pragma unroll
  for (int m4 = 0; m4 < 8; ++m4)
    *(float4*)&kp[(size_t)row * 32 + m4 * 4] = *(float4*)&acck[4 * m4];
  diagk[row] = dk;
  for (int off = 32; off; off >>= 1) bmax = fmaxf(bmax, __shfl_xor(bmax, off));
  if (tid == 0) part[blockIdx.x] = bmax;
}

__global__ void k_maxred(const float* __restrict__ part, float* __restrict__ gmax) {
  float m = -3.4e38f;
  for (int i = threadIdx.x; i < BHS / 64; i += 256) m = fmaxf(m, part[i]);
  __shared__ float red[256];
  red[threadIdx.x] = m;
  __syncthreads();
  for (int s = 128; s; s >>= 1) {
    if (threadIdx.x < s) red[threadIdx.x] = fmaxf(red[threadIdx.x], red[threadIdx.x + s]);
    __syncthreads();
  }
  if (!threadIdx.x) gmax[0] = red[0];
}

// ---------------- kp-finalize + per-chunk sums; accumulation from L1-hot global ----------------
__global__ void __launch_bounds__(256) k_csfin(const float* __restrict__ diagk,
                      const float* __restrict__ gmax, const float* __restrict__ v,
                      float* __restrict__ kp, float* __restrict__ ckv) {
  int blk = blockIdx.x;
  int bh = blk / NC, c = blk % NC;
  int tid = threadIdx.x;
  int base = bh * S_ + c * CHUNK;
  float gm = gmax[0];
  {
    int row = tid >> 3, m4 = tid & 7;            // 32 rows x 8 float4
    float4 dash = *(const float4*)&kp[(size_t)(base + row) * 32 + m4 * 4];
    float dg = diagk[base + row] + gm;
    float4 fin;
    fin.x = RATIO * (expf(dash.x - dg) + 1e-4f);
    fin.y = RATIO * (expf(dash.y - dg) + 1e-4f);
    fin.z = RATIO * (expf(dash.z - dg) + 1e-4f);
    fin.w = RATIO * (expf(dash.w - dg) + 1e-4f);
    *(float4*)&kp[(size_t)(base + row) * 32 + m4 * 4] = fin;
  }
  __syncthreads();   // block-level global visibility
  int m0 = tid >> 4, d0 = tid & 15;
  int m1 = m0 + 16;
  float a0 = 0.f, a1 = 0.f, az0 = 0.f, az1 = 0.f;
  for (int t = 0; t < CHUNK; ++t) {
    const float* kr = kp + (size_t)(base + t) * 32;
    float k0 = kr[m0];
    float k1 = kr[m1];
    float vv = v[(size_t)(base + t) * 16 + d0];
    a0 += k0 * vv;
    a1 += k1 * vv;
    if (d0 == 0) { az0 += k0; az1 += k1; }
  }
  float* outp = ckv + (size_t)blk * STATE;
  outp[m0 * 16 + d0] = a0;
  outp[m1 * 16 + d0] = a1;
  if (d0 == 0) { outp[512 + m0] = az0; outp[512 + m1] = az1; }
}

// ---------------- exclusive prefix over chunks (in place), one scan-column per thread ----------------
__global__ void k_prefix(float* __restrict__ ckv) {
  int idx = blockIdx.x * 256 + threadIdx.x;      // 17 blocks x 256 = 4352 = BH*544
  int bh = idx / STATE, c = idx % STATE;
  float run = 0.f;
  for (int j0 = 0; j0 < NC; j0 += 16) {
    float tb[16];
#pragma unroll
    for (int jj = 0; jj < 16; ++jj) tb[jj] = ckv[((size_t)bh * NC + j0 + jj) * STATE + c];
#pragma unroll
    for (int jj = 0; jj < 16; ++jj) {
      ckv[((size_t)bh * NC + j0 + jj) * STATE + c] = run;
      run += tb[jj];
    }
  }
}

// ---------------- within-chunk causal attention via MFMA (CHUNK=32; 4 chunks/block, 1 wave each) ----
__global__ void __launch_bounds__(256) k_attn(const float* __restrict__ qp,
                                              const float* __restrict__ kp,
                                              const float* __restrict__ v,
                                              const float* __restrict__ ckv,
                                              float* __restrict__ attn) {
  __shared__ __align__(16) float sP[4][32 * 33 + 4];
  int tid = threadIdx.x;
  int w = tid >> 6;                 // wave -> chunk
  int L = tid & 63;
  int half = L >> 5;
  int n = L & 31;
  int chunk = blockIdx.x * 4 + w;
  int bh = chunk / NC, c = chunk % NC;
  int base = bh * S_ + c * CHUNK;

  const float* qrow = qp + (size_t)(base + n) * 32 + half * 8;
  const float* krow = kp + (size_t)(base + n) * 32 + half * 8;
  short8 a1, a2, b1, b2;
  {
    float4 q0 = *(const float4*)&qrow[0];
    float4 q1 = *(const float4*)&qrow[4];
    float4 q2 = *(const float4*)&qrow[16];
    float4 q3 = *(const float4*)&qrow[20];
    float4 k0 = *(const float4*)&krow[0];
    float4 k1 = *(const float4*)&krow[4];
    float4 k2 = *(const float4*)&krow[16];
    float4 k3 = *(const float4*)&krow[20];
    a1[0]=(short)f2bf(q0.x); a1[1]=(short)f2bf(q0.y); a1[2]=(short)f2bf(q0.z); a1[3]=(short)f2bf(q0.w);
    a1[4]=(short)f2bf(q1.x); a1[5]=(short)f2bf(q1.y); a1[6]=(short)f2bf(q1.z); a1[7]=(short)f2bf(q1.w);
    a2[0]=(short)f2bf(q2.x); a2[1]=(short)f2bf(q2.y); a2[2]=(short)f2bf(q2.z); a2[3]=(short)f2bf(q2.w);
    a2[4]=(short)f2bf(q3.x); a2[5]=(short)f2bf(q3.y); a2[6]=(short)f2bf(q3.z); a2[7]=(short)f2bf(q3.w);
    b1[0]=(short)f2bf(k0.x); b1[1]=(short)f2bf(k0.y); b1[2]=(short)f2bf(k0.z); b1[3]=(short)f2bf(k0.w);
    b1[4]=(short)f2bf(k1.x); b1[5]=(short)f2bf(k1.y); b1[6]=(short)f2bf(k1.z); b1[7]=(short)f2bf(k1.w);
    b2[0]=(short)f2bf(k2.x); b2[1]=(short)f2bf(k2.y); b2[2]=(short)f2bf(k2.z); b2[3]=(short)f2bf(k2.w);
    b2[4]=(short)f2bf(k3.x); b2[5]=(short)f2bf(k3.y); b2[6]=(short)f2bf(k3.z); b2[7]=(short)f2bf(k3.w);
  }
  floatx16 P;
#pragma unroll
  for (int i = 0; i < 16; ++i) P[i] = 0.f;
  P = __builtin_amdgcn_mfma_f32_32x32x16_bf16(a1, b1, P, 0, 0, 0);
  P = __builtin_amdgcn_mfma_f32_32x32x16_bf16(a2, b2, P, 0, 0, 0);

  float* sp = &sP[w][0];
#pragma unroll
  for (int r = 0; r < 16; ++r) {
    int i = (r & 3) + 8 * (r >> 2) + 4 * half;
    sp[i * 33 + n] = (n <= i) ? P[r] : 0.f;
  }
  __syncthreads();
  short8 pa1, pa2;
#pragma unroll
  for (int j = 0; j < 8; ++j) {
    pa1[j] = (short)f2bf(sp[n * 33 + half * 8 + j]);
    pa2[j] = (short)f2bf(sp[n * 33 + 16 + half * 8 + j]);
  }

  const float* cs = ckv + (size_t)chunk * STATE;
  short8 vb1, vb2, sb1, sb2;
#pragma unroll
  for (int j = 0; j < 8; ++j) {
    int t1 = half * 8 + j, t2 = 16 + half * 8 + j;
    float x1 = (n < 16) ? v[(size_t)(base + t1) * 16 + n] : (n == 16 ? 1.f : 0.f);
    float x2 = (n < 16) ? v[(size_t)(base + t2) * 16 + n] : (n == 16 ? 1.f : 0.f);
    vb1[j] = (short)f2bf(x1);
    vb2[j] = (short)f2bf(x2);
    float y1 = (n < 16) ? cs[t1 * 16 + n] : (n == 16 ? cs[512 + t1] : 0.f);
    float y2 = (n < 16) ? cs[t2 * 16 + n] : (n == 16 ? cs[512 + t2] : 0.f);
    sb1[j] = (short)f2bf(y1);
    sb2[j] = (short)f2bf(y2);
  }

  floatx16 O;
#pragma unroll
  for (int i = 0; i < 16; ++i) O[i] = 0.f;
  O = __builtin_amdgcn_mfma_f32_32x32x16_bf16(pa1, vb1, O, 0, 0, 0);
  O = __builtin_amdgcn_mfma_f32_32x32x16_bf16(pa2, vb2, O, 0, 0, 0);
  O = __builtin_amdgcn_mfma_f32_32x32x16_bf16(a1, sb1, O, 0, 0, 0);
  O = __builtin_amdgcn_mfma_f32_32x32x16_bf16(a2, sb2, O, 0, 0, 0);

  int srcl = 16 + 32 * half;
  float res[16];
#pragma unroll
  for (int r = 0; r < 16; ++r) {
    float den = __shfl(O[r], srcl, 64);
    res[r] = O[r] / den;
  }
  if (n < 16) {
    int b = bh >> 2, head = bh & 3;
#pragma unroll
    for (int r = 0; r < 16; ++r) {
      int i = (r & 3) + 8 * (r >> 2) + 4 * half;
      attn[((size_t)(b * S_ + c * CHUNK + i)) * 64 + head * 16 + n] = res[r];
    }
  }
}

// ---------------- attn @ wo + bo + residual + LayerNorm2, fused ----------------
__global__ void __launch_bounds__(256) k_wo_ln(const float* __restrict__ attn,
                        const float* __restrict__ wo, const float* __restrict__ bo,
                        const float* __restrict__ tok, const float* __restrict__ g,
                        const float* __restrict__ bb,
                        float* __restrict__ tok2, float* __restrict__ h2) {
  __shared__ __align__(16) float sA[32 * 68];
  int tid = threadIdx.x;
  int tbase = blockIdx.x * 32;
  for (int e = tid; e < 512; e += 256) {
    int row = e >> 4, c4 = e & 15;
    *(float4*)&sA[row * 68 + c4 * 4] = *(const float4*)&attn[(tbase + row) * 64 + c4 * 4];
  }
  __syncthreads();
  int tg = tid >> 5;
  int cg = tid & 31;
  int c0 = cg * 2, c1 = c0 + 1;
  float a0[4], a1[4];
#pragma unroll
  for (int i = 0; i < 4; ++i) { a0[i] = 0.f; a1[i] = 0.f; }
  for (int dc = 0; dc < 16; ++dc) {
    float4 af[4];
#pragma unroll
    for (int i = 0; i < 4; ++i) af[i] = *(const float4*)&sA[(tg * 4 + i) * 68 + dc * 4];
    float w0[4], w1v[4];
#pragma unroll
    for (int dd = 0; dd < 4; ++dd) {
      int d = dc * 4 + dd;
      w0[dd] = wo[d * 64 + c0]; w1v[dd] = wo[d * 64 + c1];
    }
#pragma unroll
    for (int i = 0; i < 4; ++i) {
      const float* ap = (const float*)&af[i];
#pragma unroll
      for (int dd = 0; dd < 4; ++dd) { a0[i] += ap[dd] * w0[dd]; a1[i] += ap[dd] * w1v[dd]; }
    }
  }
  float bo0 = bo[c0], bo1 = bo[c1];
  float g0 = g[c0], g1 = g[c1], be0 = bb[c0], be1 = bb[c1];
#pragma unroll
  for (int i = 0; i < 4; ++i) {
    int token = tbase + tg * 4 + i;
    float t0 = tok[token * 64 + c0] + a0[i] + bo0;
    float t1 = tok[token * 64 + c1] + a1[i] + bo1;
    float s1 = t0 + t1, s2 = t0 * t0 + t1 * t1;
    for (int off = 16; off; off >>= 1) {
      s1 += __shfl_xor(s1, off, 32);
      s2 += __shfl_xor(s2, off, 32);
    }
    float mu = s1 * (1.f / 64.f);
    float var = s2 * (1.f / 64.f) - mu * mu;
    float rs = rsqrtf(var + 1e-5f);
    tok2[token * 64 + c0] = t0;
    tok2[token * 64 + c1] = t1;
    h2[token * 64 + c0] = (t0 - mu) * rs * g0 + be0;
    h2[token * 64 + c1] = (t1 - mu) * rs * g1 + be1;
  }
}

// ---------------- FF phase 1 via MFMA: G = gelu(h2 @ W1 + b1), bf16 out ----------------
// Block = 4 waves x 32 tokens; wave w covers cols w*64..w*64+63 (2 C-tiles, 4 chained MFMAs each).
__global__ void __launch_bounds__(256) k_ff1(const float* __restrict__ h2,
                                             const float* __restrict__ w1,
                                             const float* __restrict__ b1,
                                             bf16* __restrict__ G) {
  int tid = threadIdx.x;
  int w = tid >> 6;
  int L = tid & 63;
  int half = L >> 5;
  int n = L & 31;
  int tbase = blockIdx.x * 32;

  // A-frags: h2[token = tbase+n][k = c*16 + half*8 + j], fp32 -> bf16
  short8 a[4];
  {
    const float* hrow = h2 + (size_t)(tbase + n) * 64 + half * 8;
#pragma unroll
    for (int c = 0; c < 4; ++c) {
      float4 f0 = *(const float4*)&hrow[c * 16];
      float4 f1 = *(const float4*)&hrow[c * 16 + 4];
      a[c][0] = (short)f2bf(f0.x); a[c][1] = (short)f2bf(f0.y);
      a[c][2] = (short)f2bf(f0.z); a[c][3] = (short)f2bf(f0.w);
      a[c][4] = (short)f2bf(f1.x); a[c][5] = (short)f2bf(f1.y);
      a[c][6] = (short)f2bf(f1.z); a[c][7] = (short)f2bf(f1.w);
    }
  }

#pragma unroll
  for (int ct = 0; ct < 2; ++ct) {
    int col = w * 64 + ct * 32 + n;
    // B-frags: w1[k = c*16 + half*8 + j][col]
    short8 bfrag[4];
#pragma unroll
    for (int c = 0; c < 4; ++c) {
#pragma unroll
      for (int j = 0; j < 8; ++j)
        bfrag[c][j] = (short)f2bf(w1[(c * 16 + half * 8 + j) * 256 + col]);
    }
    floatx16 acc;
#pragma unroll
    for (int i = 0; i < 16; ++i) acc[i] = 0.f;
    acc = __builtin_amdgcn_mfma_f32_32x32x16_bf16(a[0], bfrag[0], acc, 0, 0, 0);
    acc = __builtin_amdgcn_mfma_f32_32x32x16_bf16(a[1], bfrag[1], acc, 0, 0, 0);
    acc = __builtin_amdgcn_mfma_f32_32x32x16_bf16(a[2], bfrag[2], acc, 0, 0, 0);
    acc = __builtin_amdgcn_mfma_f32_32x32x16_bf16(a[3], bfrag[3], acc, 0, 0, 0);
    float bias = b1[col];
#pragma unroll
    for (int r = 0; r < 16; ++r) {
      int row = (r & 3) + 8 * (r >> 2) + 4 * half;
      float xg = acc[r] + bias;
      float gl = 0.5f * xg * (1.f + erff(xg * 0.70710678118654752f));
      G[(size_t)(tbase + row) * 256 + col] = __float2bfloat16(gl);
    }
  }
}

// ---------------- Gavg: mean over T of the 8 G rows feeding each pool element ----------------
__global__ void k_gavg(const bf16* __restrict__ G, float* __restrict__ Gavg) {
  int blk = blockIdx.x;                 // 4608 = B*64*36
  int tid = threadIdx.x;                // column 0..255
  int b = blk / 2304;
  int rem = blk % 2304;
  int ch = rem / 36, jp = rem % 36;
  size_t gbase = ((size_t)b * 18432 + ch * 288 + jp) * 256 + tid;
  float s = 0.f;
#pragma unroll
  for (int t = 0; t < 8; ++t) s += __bfloat162float(G[gbase + (size_t)t * 36 * 256]);
  Gavg[(size_t)blk * 256 + tid] = s * 0.125f;
}

// ---------------- pool = mean_t(tok2) + Gavg @ W2 + b2 (FF2 folded 8x by linearity) ----------------
__global__ void __launch_bounds__(256) k_pool2(const float* __restrict__ Gavg,
                        const float* __restrict__ tok2, const float* __restrict__ w2,
                        const float* __restrict__ b2, float* __restrict__ pool) {
  __shared__ __align__(16) float sG[18 * 256];     // 18.4 KB
  __shared__ __align__(16) float sRed[4 * 18 * 64]; // 18.4 KB
  int blk = blockIdx.x;
  int b = blk / 128;
  int rem = blk % 128;
  int ch = rem >> 1, jph = rem & 1;
  int tid = threadIdx.x;
  size_t grow0 = ((size_t)(b * 64 + ch) * 36 + jph * 18) * 256;
  for (int e = tid; e < 1152; e += 256) {          // 18 rows x 64 float4
    int row = e >> 6, c4 = e & 63;
    *(float4*)&sG[row * 256 + c4 * 4] = *(const float4*)&Gavg[grow0 + row * 256 + c4 * 4];
  }
  __syncthreads();
  int kg = tid >> 6, dd = tid & 63;
  float acc[18];
#pragma unroll
  for (int i = 0; i < 18; ++i) acc[i] = 0.f;
  for (int k4 = 0; k4 < 16; ++k4) {
    int k = kg * 64 + k4 * 4;
    float w0 = w2[(k + 0) * 64 + dd];
    float w1 = w2[(k + 1) * 64 + dd];
    float w2v = w2[(k + 2) * 64 + dd];
    float w3 = w2[(k + 3) * 64 + dd];
#pragma unroll
    for (int i = 0; i < 18; ++i) {
      float4 gf = *(const float4*)&sG[i * 256 + k];   // wave-wide broadcast
      acc[i] += gf.x * w0 + gf.y * w1 + gf.z * w2v + gf.w * w3;
    }
  }
#pragma unroll
  for (int i = 0; i < 18; ++i) sRed[(kg * 18 + i) * 64 + dd] = acc[i];
  __syncthreads();
  for (int o = tid; o < 1152; o += 256) {
    int jp18 = o >> 6, d2 = o & 63;
    float gsum = sRed[(0 * 18 + jp18) * 64 + d2] + sRed[(1 * 18 + jp18) * 64 + d2]
               + sRed[(2 * 18 + jp18) * 64 + d2] + sRed[(3 * 18 + jp18) * 64 + d2];
    int p = (jph * 18 + jp18) * 64 + d2;
    size_t tbase = (size_t)b * 1179648 + (size_t)ch * 18432 + p;
    float ts = 0.f;
#pragma unroll
    for (int t = 0; t < 8; ++t) ts += tok2[tbase + t * 2304];
    pool[((size_t)(b * 64 + ch)) * HW + p] = ts * 0.125f + gsum + b2[d2];
  }
}

// ---------------- conv(5x5,pad2) + global-avg-pool folded ----------------
__global__ void __launch_bounds__(256) k_convsum(const float* __restrict__ pool,
                                                 const float* __restrict__ x,
                                                 const float* __restrict__ w,
                                                 float* __restrict__ partial) {
  int blk = blockIdx.x;          // b*65 + ch
  int b = blk / 65, ch = blk % 65;
  int tid = threadIdx.x;
  __shared__ float cls[25];
  __shared__ float red[256];
  if (tid < 25) {
    int ry = tid / 5, rx = tid % 5;
    int kh0 = (ry <= 2) ? 0 : (ry == 3 ? 1 : 2);
    int kh1 = (ry >= 2) ? 4 : (ry == 1 ? 3 : 2);
    int kw0 = (rx <= 2) ? 0 : (rx == 3 ? 1 : 2);
    int kw1 = (rx >= 2) ? 4 : (rx == 1 ? 3 : 2);
    float s = 0.f;
    for (int kh = kh0; kh <= kh1; ++kh)
      for (int kw = kw0; kw <= kw1; ++kw)
        s += w[ch * 25 + kh * 5 + kw];
    cls[tid] = s;
  }
  __syncthreads();
  const float* pc = (ch < 64) ? (pool + ((size_t)(b * 64 + ch)) * HW)
                              : (x + (size_t)b * 3 * S_ + 2 * S_);
  float acc = 0.f;
#pragma unroll
  for (int e = tid; e < HW; e += 256) {
    int iy = e / 48, ix = e % 48;
    int ry = (iy == 0) ? 0 : (iy == 1) ? 1 : (iy <= 45) ? 2 : (iy == 46) ? 3 : 4;
    int rx = (ix == 0) ? 0 : (ix == 1) ? 1 : (ix <= 45) ? 2 : (ix == 46) ? 3 : 4;
    acc += pc[e] * cls[ry * 5 + rx];
  }
  red[tid] = acc;
  __syncthreads();
  for (int s = 128; s; s >>= 1) {
    if (tid < s) red[tid] += red[tid + s];
    __syncthreads();
  }
  if (!tid) partial[blk] = red[0];
}

// ---------------- reduce 65 channel sums per b + readout ----------------
__global__ void k_final(const float* __restrict__ partial, const float* __restrict__ tgt_b,
                        const float* __restrict__ rd_w, const float* __restrict__ rd_b,
                        float* __restrict__ out) {
  int b = blockIdx.x;
  int lane = threadIdx.x;
  float s = (lane < 65) ? partial[b * 65 + lane] : 0.f;
  for (int off = 32; off; off >>= 1) s += __shfl_down(s, off, 64);
  __shared__ float r2;
  if (lane == 64) r2 = s;
  __syncthreads();
  if (!lane) {
    float tot = s + r2;
    float mean = tot / 2304.f + tgt_b[0];
    out[b] = mean * rd_w[0] + rd_b[0];
  }
}

extern "C" void kernel_launch(void* const* d_in, const int* in_sizes, int n_in,
                              void* d_out, int out_size, void* d_ws, size_t ws_size,
                              hipStream_t stream) {
  const float* x     = (const float*)d_in[0];
  const float* pre_w = (const float*)d_in[1];
  const float* pre_b = (const float*)d_in[2];
  const float* ln1_g = (const float*)d_in[3];
  const float* ln1_b = (const float*)d_in[4];
  const float* wq    = (const float*)d_in[5];
  const float* wk    = (const float*)d_in[6];
  const float* wv    = (const float*)d_in[7];
  const float* wo    = (const float*)d_in[8];
  const float* bo    = (const float*)d_in[9];
  const float* proj  = (const float*)d_in[10];
  const float* ln2_g = (const float*)d_in[11];
  const float* ln2_b = (const float*)d_in[12];
  const float* ff_w1 = (const float*)d_in[13];
  const float* ff_b1 = (const float*)d_in[14];
  const float* ff_w2 = (const float*)d_in[15];
  const float* ff_b2 = (const float*)d_in[16];
  const float* tgt_w = (const float*)d_in[17];
  const float* tgt_b = (const float*)d_in[18];
  const float* rd_w  = (const float*)d_in[19];
  const float* rd_b  = (const float*)d_in[20];
  float* out = (float*)d_out;

  float* ws = (float*)d_ws;
  float* tok   = ws;
  float* v     = ws + (size_t)BSD;
  float* q     = ws + 2 * (size_t)BSD;
  float* Gavg  = ws + 2 * (size_t)BSD;          // q dead after k_feat
  float* pool  = Gavg + 1179648;                // 294912 floats
  float* k     = ws + 3 * (size_t)BSD;
  float* h     = ws + 4 * (size_t)BSD;          // LN1 out; dead after k_qkv
  float* kp    = ws + 4 * (size_t)BSD;          // 2 BSD; written by k_feat after h dead
  float* qp    = ws + 6 * (size_t)BSD;          // 2 BSD; dead after k_attn
  bf16*  G     = (bf16*)(ws + 6 * (size_t)BSD); // 9.4M bf16 (reuses qp)
  float* ckv   = ws + 8 * (size_t)BSD;          // 2506752 floats; dead after k_attn
  float* tok2  = ws + 8 * (size_t)BSD;          // written by k_wo_ln (ckv dead)
  float* attnb = k;                             // k dead after k_feat
  float* h2    = ws + 4 * (size_t)BSD;          // kp dead after k_attn
  float* smalls = ws + 9 * (size_t)BSD + 147456;
  float* diagk = smalls;                        // 147456; k_feat -> k_csfin
  float* part  = diagk + BHS;                   // 2304 used
  float* gmax  = part + BHSM / 256;             // 1
  float* partial = gmax + 64;                   // 130

  k_preln<<<dim3(BS / 4), dim3(256), 0, stream>>>(x, pre_w, pre_b, ln1_g, ln1_b, tok, h);
  k_qkv<<<dim3(BS / 32), dim3(256), 0, stream>>>(h, wq, wk, wv, q, k, v);
  k_feat<<<dim3(BHS / 64), dim3(64), 0, stream>>>(q, k, proj, qp, kp, diagk, part);
  k_maxred<<<dim3(1), dim3(256), 0, stream>>>(part, gmax);
  k_csfin<<<dim3(BH * NC), dim3(256), 0, stream>>>(diagk, gmax, v, kp, ckv);
  k_prefix<<<dim3(BH * STATE / 256), dim3(256), 0, stream>>>(ckv);
  k_attn<<<dim3(BH * NC / 4), dim3(256), 0, stream>>>(qp, kp, v, ckv, attnb);
  k_wo_ln<<<dim3(BS / 32), dim3(256), 0, stream>>>(attnb, wo, bo, tok, ln2_g, ln2_b, tok2, h2);
  k_ff1<<<dim3(BS / 32), dim3(256), 0, stream>>>(h2, ff_w1, ff_b1, G);
  k_gavg<<<dim3(B_ * 64 * 36), dim3(256), 0, stream>>>(G, Gavg);
  k_pool2<<<dim3(B_ * 64 * 2), dim3(256), 0, stream>>>(Gavg, tok2, ff_w2, ff_b2, pool);
  k_convsum<<<dim3(B_ * 65), dim3(256), 0, stream>>>(pool, x, tgt_w, partial);
  k_final<<<dim3(B_), dim3(128), 0, stream>>>(partial, tgt_b, rd_w, rd_b, out);
}

// Round 12
// 257.573 us; speedup vs baseline: 1.3019x; 1.0930x over previous
//
#include <hip/hip_runtime.h>
#include <hip/hip_bf16.h>
#include <math.h>

typedef __hip_bfloat16 bf16;
typedef __attribute__((ext_vector_type(8))) short short8;
typedef __attribute__((ext_vector_type(16))) float floatx16;

// Problem constants
constexpr int B_   = 2;
constexpr int T_   = 8;
constexpr int HW   = 48 * 48;          // 2304
constexpr int S_   = T_ * HW;          // 18432
constexpr int D_   = 64;
constexpr int NH   = 4;
constexpr int DH   = 16;
constexpr int M_   = 32;
constexpr int BS   = B_ * S_;          // 36864 tokens
constexpr int BSD  = BS * D_;          // 2359296
constexpr int BH   = B_ * NH;          // 8 sequences
constexpr int BHS  = BH * S_;          // 147456 rows
constexpr int BHSM = BHS * M_;         // 4718592
constexpr int CHUNK = 32;
constexpr int NC   = S_ / CHUNK;       // 576 chunks per sequence
constexpr int STATE = M_ * DH + M_;    // 544 floats of scan state
constexpr float DN = 0.5f;                         // 16^-0.25
constexpr float RATIO = 0.17677669529663687f;      // 32^-0.5

__device__ __forceinline__ unsigned short f2bf(float f) {
  bf16 h = __float2bfloat16(f);
  return *reinterpret_cast<unsigned short*>(&h);
}

// ---------------- fused: 1x1x1 conv3d + softplus + LayerNorm1 ----------------
__global__ void k_preln(const float* __restrict__ x, const float* __restrict__ pw,
                        const float* __restrict__ pb, const float* __restrict__ g,
                        const float* __restrict__ bb,
                        float* __restrict__ tok, float* __restrict__ h) {
  int token = blockIdx.x * 4 + (threadIdx.x >> 6);
  int lane = threadIdx.x & 63;
  int f = token * 64 + lane;          // flat over B*D*S
  int b = f / (D_ * S_);
  int r = f % (D_ * S_);
  int d = r / S_;
  int pos = r % S_;
  const float* xb = x + b * 3 * S_ + pos;
  float a = xb[0] * pw[d * 3 + 0] + xb[S_] * pw[d * 3 + 1] + xb[2 * S_] * pw[d * 3 + 2]
          + pb[d];
  float t = fmaxf(a, 0.f) + log1pf(expf(-fabsf(a)));  // softplus
  tok[f] = t;
  float s1 = t, s2 = t * t;
  for (int off = 32; off; off >>= 1) {
    s1 += __shfl_xor(s1, off);
    s2 += __shfl_xor(s2, off);
  }
  float mu = s1 * (1.f / 64.f);
  float var = s2 * (1.f / 64.f) - mu * mu;
  float rs = rsqrtf(var + 1e-5f);
  h[f] = (t - mu) * rs * g[lane] + bb[lane];
}

// ---------------- QKV projections via MFMA: 3 waves = {wq,wk,wv}, 32 tokens/block ----------------
__global__ void __launch_bounds__(192) k_qkv(const float* __restrict__ h,
                      const float* __restrict__ wq, const float* __restrict__ wk,
                      const float* __restrict__ wv,
                      float* __restrict__ q, float* __restrict__ k, float* __restrict__ v) {
  int tid = threadIdx.x;
  int w = tid >> 6;                 // wave -> matrix
  int L = tid & 63;
  int half = L >> 5;
  int n = L & 31;
  int tbase = blockIdx.x * 32;
  const float* wm = (w == 0) ? wq : (w == 1) ? wk : wv;
  float* outm = (w == 0) ? q : (w == 1) ? k : v;

  // A-frags: h[token = tbase+n][kk = c*16 + half*8 + j]
  short8 a[4];
  {
    const float* hrow = h + (size_t)(tbase + n) * 64 + half * 8;
#pragma unroll
    for (int c = 0; c < 4; ++c) {
      float4 f0 = *(const float4*)&hrow[c * 16];
      float4 f1 = *(const float4*)&hrow[c * 16 + 4];
      a[c][0] = (short)f2bf(f0.x); a[c][1] = (short)f2bf(f0.y);
      a[c][2] = (short)f2bf(f0.z); a[c][3] = (short)f2bf(f0.w);
      a[c][4] = (short)f2bf(f1.x); a[c][5] = (short)f2bf(f1.y);
      a[c][6] = (short)f2bf(f1.z); a[c][7] = (short)f2bf(f1.w);
    }
  }
#pragma unroll
  for (int ct = 0; ct < 2; ++ct) {
    int col = ct * 32 + n;
    short8 bfrag[4];
#pragma unroll
    for (int c = 0; c < 4; ++c) {
#pragma unroll
      for (int j = 0; j < 8; ++j)
        bfrag[c][j] = (short)f2bf(wm[(c * 16 + half * 8 + j) * 64 + col]);
    }
    floatx16 acc;
#pragma unroll
    for (int i = 0; i < 16; ++i) acc[i] = 0.f;
    acc = __builtin_amdgcn_mfma_f32_32x32x16_bf16(a[0], bfrag[0], acc, 0, 0, 0);
    acc = __builtin_amdgcn_mfma_f32_32x32x16_bf16(a[1], bfrag[1], acc, 0, 0, 0);
    acc = __builtin_amdgcn_mfma_f32_32x32x16_bf16(a[2], bfrag[2], acc, 0, 0, 0);
    acc = __builtin_amdgcn_mfma_f32_32x32x16_bf16(a[3], bfrag[3], acc, 0, 0, 0);
    int head = col >> 4, di = col & 15;
#pragma unroll
    for (int r = 0; r < 16; ++r) {
      int row = (r & 3) + 8 * (r >> 2) + 4 * half;
      int token = tbase + row;
      int b = token / S_, s = token % S_;
      outm[((size_t)(b * NH + head) * S_ + s) * DH + di] = acc[r];
    }
  }
}

// ---------------- feature map, row-per-thread: qp final + raw dash_k + diag_k + block max ----------------
__global__ void __launch_bounds__(64) k_feat(const float* __restrict__ q,
                      const float* __restrict__ k, const float* __restrict__ proj,
                      float* __restrict__ qp, float* __restrict__ kp,
                      float* __restrict__ diagk, float* __restrict__ part) {
  __shared__ __align__(16) float sPT[16 * 32];   // proj^T [d][m]
  int tid = threadIdx.x;
  for (int e = tid; e < 512; e += 64) {
    int d = e >> 5, m = e & 31;
    sPT[d * 32 + m] = proj[m * 16 + d];          // m-fastest write: conflict-free
  }
  __syncthreads();
  int row = blockIdx.x * 64 + tid;
  float qv[16], kv[16];
  float dq = 0.f, dk = 0.f;
  {
    const float4* q4 = (const float4*)(q + (size_t)row * 16);
    const float4* k4 = (const float4*)(k + (size_t)row * 16);
#pragma unroll
    for (int i = 0; i < 4; ++i) {
      float4 t4 = q4[i];
      qv[4*i] = t4.x * DN; qv[4*i+1] = t4.y * DN; qv[4*i+2] = t4.z * DN; qv[4*i+3] = t4.w * DN;
      float4 u4 = k4[i];
      kv[4*i] = u4.x * DN; kv[4*i+1] = u4.y * DN; kv[4*i+2] = u4.z * DN; kv[4*i+3] = u4.w * DN;
    }
#pragma unroll
    for (int d = 0; d < 16; ++d) { dq += qv[d] * qv[d]; dk += kv[d] * kv[d]; }
    dq *= 0.5f; dk *= 0.5f;
  }
  float accq[32], acck[32];
#pragma unroll
  for (int m = 0; m < 32; ++m) { accq[m] = 0.f; acck[m] = 0.f; }
#pragma unroll
  for (int d = 0; d < 16; ++d) {
    float qd = qv[d], kd = kv[d];
    const float4* pr = (const float4*)&sPT[d * 32];
#pragma unroll
    for (int m4 = 0; m4 < 8; ++m4) {
      float4 p = pr[m4];                          // wave-uniform address: broadcast
      accq[4*m4+0] += qd * p.x; accq[4*m4+1] += qd * p.y;
      accq[4*m4+2] += qd * p.z; accq[4*m4+3] += qd * p.w;
      acck[4*m4+0] += kd * p.x; acck[4*m4+1] += kd * p.y;
      acck[4*m4+2] += kd * p.z; acck[4*m4+3] += kd * p.w;
    }
  }
  float mx = accq[0];
#pragma unroll
  for (int m = 1; m < 32; ++m) mx = fmaxf(mx, accq[m]);
#pragma unroll
  for (int m4 = 0; m4 < 8; ++m4) {
    float4 o;
    o.x = RATIO * (expf(accq[4*m4+0] - dq - mx) + 1e-4f);
    o.y = RATIO * (expf(accq[4*m4+1] - dq - mx) + 1e-4f);
    o.z = RATIO * (expf(accq[4*m4+2] - dq - mx) + 1e-4f);
    o.w = RATIO * (expf(accq[4*m4+3] - dq - mx) + 1e-4f);
    *(float4*)&qp[(size_t)row * 32 + m4 * 4] = o;
  }
  float bmax = acck[0];
#pragma unroll
  for (int m = 1; m < 32; ++m) bmax = fmaxf(bmax, acck[m]);
#pragma unroll
  for (int m4 = 0; m4 < 8; ++m4)
    *(float4*)&kp[(size_t)row * 32 + m4 * 4] = *(float4*)&acck[4 * m4];
  diagk[row] = dk;
  for (int off = 32; off; off >>= 1) bmax = fmaxf(bmax, __shfl_xor(bmax, off));
  if (tid == 0) part[blockIdx.x] = bmax;
}

__global__ void k_maxred(const float* __restrict__ part, float* __restrict__ gmax) {
  float m = -3.4e38f;
  for (int i = threadIdx.x; i < BHS / 64; i += 256) m = fmaxf(m, part[i]);
  __shared__ float red[256];
  red[threadIdx.x] = m;
  __syncthreads();
  for (int s = 128; s; s >>= 1) {
    if (threadIdx.x < s) red[threadIdx.x] = fmaxf(red[threadIdx.x], red[threadIdx.x + s]);
    __syncthreads();
  }
  if (!threadIdx.x) gmax[0] = red[0];
}

// ---------------- kp-finalize + per-chunk sums; accumulation from L1-hot global ----------------
__global__ void __launch_bounds__(256) k_csfin(const float* __restrict__ diagk,
                      const float* __restrict__ gmax, const float* __restrict__ v,
                      float* __restrict__ kp, float* __restrict__ ckv) {
  int blk = blockIdx.x;
  int bh = blk / NC, c = blk % NC;
  int tid = threadIdx.x;
  int base = bh * S_ + c * CHUNK;
  float gm = gmax[0];
  {
    int row = tid >> 3, m4 = tid & 7;            // 32 rows x 8 float4
    float4 dash = *(const float4*)&kp[(size_t)(base + row) * 32 + m4 * 4];
    float dg = diagk[base + row] + gm;
    float4 fin;
    fin.x = RATIO * (expf(dash.x - dg) + 1e-4f);
    fin.y = RATIO * (expf(dash.y - dg) + 1e-4f);
    fin.z = RATIO * (expf(dash.z - dg) + 1e-4f);
    fin.w = RATIO * (expf(dash.w - dg) + 1e-4f);
    *(float4*)&kp[(size_t)(base + row) * 32 + m4 * 4] = fin;
  }
  __syncthreads();   // block-level global visibility
  int m0 = tid >> 4, d0 = tid & 15;
  int m1 = m0 + 16;
  float a0 = 0.f, a1 = 0.f, az0 = 0.f, az1 = 0.f;
  for (int t = 0; t < CHUNK; ++t) {
    const float* kr = kp + (size_t)(base + t) * 32;
    float k0 = kr[m0];
    float k1 = kr[m1];
    float vv = v[(size_t)(base + t) * 16 + d0];
    a0 += k0 * vv;
    a1 += k1 * vv;
    if (d0 == 0) { az0 += k0; az1 += k1; }
  }
  float* outp = ckv + (size_t)blk * STATE;
  outp[m0 * 16 + d0] = a0;
  outp[m1 * 16 + d0] = a1;
  if (d0 == 0) { outp[512 + m0] = az0; outp[512 + m1] = az1; }
}

// ---------------- exclusive prefix over chunks (in place), one scan-column per thread ----------------
__global__ void k_prefix(float* __restrict__ ckv) {
  int idx = blockIdx.x * 256 + threadIdx.x;      // 17 blocks x 256 = 4352 = BH*544
  int bh = idx / STATE, c = idx % STATE;
  float run = 0.f;
  for (int j0 = 0; j0 < NC; j0 += 16) {
    float tb[16];
#pragma unroll
    for (int jj = 0; jj < 16; ++jj) tb[jj] = ckv[((size_t)bh * NC + j0 + jj) * STATE + c];
#pragma unroll
    for (int jj = 0; jj < 16; ++jj) {
      ckv[((size_t)bh * NC + j0 + jj) * STATE + c] = run;
      run += tb[jj];
    }
  }
}

// ---------------- within-chunk causal attention via MFMA (CHUNK=32; 4 chunks/block, 1 wave each) ----
__global__ void __launch_bounds__(256) k_attn(const float* __restrict__ qp,
                                              const float* __restrict__ kp,
                                              const float* __restrict__ v,
                                              const float* __restrict__ ckv,
                                              float* __restrict__ attn) {
  __shared__ __align__(16) float sP[4][32 * 33 + 4];
  int tid = threadIdx.x;
  int w = tid >> 6;                 // wave -> chunk
  int L = tid & 63;
  int half = L >> 5;
  int n = L & 31;
  int chunk = blockIdx.x * 4 + w;
  int bh = chunk / NC, c = chunk % NC;
  int base = bh * S_ + c * CHUNK;

  const float* qrow = qp + (size_t)(base + n) * 32 + half * 8;
  const float* krow = kp + (size_t)(base + n) * 32 + half * 8;
  short8 a1, a2, b1, b2;
  {
    float4 q0 = *(const float4*)&qrow[0];
    float4 q1 = *(const float4*)&qrow[4];
    float4 q2 = *(const float4*)&qrow[16];
    float4 q3 = *(const float4*)&qrow[20];
    float4 k0 = *(const float4*)&krow[0];
    float4 k1 = *(const float4*)&krow[4];
    float4 k2 = *(const float4*)&krow[16];
    float4 k3 = *(const float4*)&krow[20];
    a1[0]=(short)f2bf(q0.x); a1[1]=(short)f2bf(q0.y); a1[2]=(short)f2bf(q0.z); a1[3]=(short)f2bf(q0.w);
    a1[4]=(short)f2bf(q1.x); a1[5]=(short)f2bf(q1.y); a1[6]=(short)f2bf(q1.z); a1[7]=(short)f2bf(q1.w);
    a2[0]=(short)f2bf(q2.x); a2[1]=(short)f2bf(q2.y); a2[2]=(short)f2bf(q2.z); a2[3]=(short)f2bf(q2.w);
    a2[4]=(short)f2bf(q3.x); a2[5]=(short)f2bf(q3.y); a2[6]=(short)f2bf(q3.z); a2[7]=(short)f2bf(q3.w);
    b1[0]=(short)f2bf(k0.x); b1[1]=(short)f2bf(k0.y); b1[2]=(short)f2bf(k0.z); b1[3]=(short)f2bf(k0.w);
    b1[4]=(short)f2bf(k1.x); b1[5]=(short)f2bf(k1.y); b1[6]=(short)f2bf(k1.z); b1[7]=(short)f2bf(k1.w);
    b2[0]=(short)f2bf(k2.x); b2[1]=(short)f2bf(k2.y); b2[2]=(short)f2bf(k2.z); b2[3]=(short)f2bf(k2.w);
    b2[4]=(short)f2bf(k3.x); b2[5]=(short)f2bf(k3.y); b2[6]=(short)f2bf(k3.z); b2[7]=(short)f2bf(k3.w);
  }
  floatx16 P;
#pragma unroll
  for (int i = 0; i < 16; ++i) P[i] = 0.f;
  P = __builtin_amdgcn_mfma_f32_32x32x16_bf16(a1, b1, P, 0, 0, 0);
  P = __builtin_amdgcn_mfma_f32_32x32x16_bf16(a2, b2, P, 0, 0, 0);

  float* sp = &sP[w][0];
#pragma unroll
  for (int r = 0; r < 16; ++r) {
    int i = (r & 3) + 8 * (r >> 2) + 4 * half;
    sp[i * 33 + n] = (n <= i) ? P[r] : 0.f;
  }
  __syncthreads();
  short8 pa1, pa2;
#pragma unroll
  for (int j = 0; j < 8; ++j) {
    pa1[j] = (short)f2bf(sp[n * 33 + half * 8 + j]);
    pa2[j] = (short)f2bf(sp[n * 33 + 16 + half * 8 + j]);
  }

  const float* cs = ckv + (size_t)chunk * STATE;
  short8 vb1, vb2, sb1, sb2;
#pragma unroll
  for (int j = 0; j < 8; ++j) {
    int t1 = half * 8 + j, t2 = 16 + half * 8 + j;
    float x1 = (n < 16) ? v[(size_t)(base + t1) * 16 + n] : (n == 16 ? 1.f : 0.f);
    float x2 = (n < 16) ? v[(size_t)(base + t2) * 16 + n] : (n == 16 ? 1.f : 0.f);
    vb1[j] = (short)f2bf(x1);
    vb2[j] = (short)f2bf(x2);
    float y1 = (n < 16) ? cs[t1 * 16 + n] : (n == 16 ? cs[512 + t1] : 0.f);
    float y2 = (n < 16) ? cs[t2 * 16 + n] : (n == 16 ? cs[512 + t2] : 0.f);
    sb1[j] = (short)f2bf(y1);
    sb2[j] = (short)f2bf(y2);
  }

  floatx16 O;
#pragma unroll
  for (int i = 0; i < 16; ++i) O[i] = 0.f;
  O = __builtin_amdgcn_mfma_f32_32x32x16_bf16(pa1, vb1, O, 0, 0, 0);
  O = __builtin_amdgcn_mfma_f32_32x32x16_bf16(pa2, vb2, O, 0, 0, 0);
  O = __builtin_amdgcn_mfma_f32_32x32x16_bf16(a1, sb1, O, 0, 0, 0);
  O = __builtin_amdgcn_mfma_f32_32x32x16_bf16(a2, sb2, O, 0, 0, 0);

  int srcl = 16 + 32 * half;
  float res[16];
#pragma unroll
  for (int r = 0; r < 16; ++r) {
    float den = __shfl(O[r], srcl, 64);
    res[r] = O[r] / den;
  }
  if (n < 16) {
    int b = bh >> 2, head = bh & 3;
#pragma unroll
    for (int r = 0; r < 16; ++r) {
      int i = (r & 3) + 8 * (r >> 2) + 4 * half;
      attn[((size_t)(b * S_ + c * CHUNK + i)) * 64 + head * 16 + n] = res[r];
    }
  }
}

// ---------------- attn @ wo + bo + residual + LayerNorm2 via MFMA ----------------
// 32 tokens/block, 2 waves = 2 col-tiles; C staged in LDS; shuffle-LN epilogue.
__global__ void __launch_bounds__(128) k_wo_ln(const float* __restrict__ attn,
                        const float* __restrict__ wo, const float* __restrict__ bo,
                        const float* __restrict__ tok, const float* __restrict__ g,
                        const float* __restrict__ bb,
                        float* __restrict__ tok2, float* __restrict__ h2) {
  __shared__ __align__(16) float sC[32 * 68];
  int tid = threadIdx.x;
  int w = tid >> 6;                 // coltile
  int L = tid & 63;
  int half = L >> 5;
  int n = L & 31;
  int tbase = blockIdx.x * 32;

  // A-frags: attn[token = tbase+n][kk]
  short8 a[4];
  {
    const float* arow = attn + (size_t)(tbase + n) * 64 + half * 8;
#pragma unroll
    for (int c = 0; c < 4; ++c) {
      float4 f0 = *(const float4*)&arow[c * 16];
      float4 f1 = *(const float4*)&arow[c * 16 + 4];
      a[c][0] = (short)f2bf(f0.x); a[c][1] = (short)f2bf(f0.y);
      a[c][2] = (short)f2bf(f0.z); a[c][3] = (short)f2bf(f0.w);
      a[c][4] = (short)f2bf(f1.x); a[c][5] = (short)f2bf(f1.y);
      a[c][6] = (short)f2bf(f1.z); a[c][7] = (short)f2bf(f1.w);
    }
  }
  int col = w * 32 + n;
  short8 bfrag[4];
#pragma unroll
  for (int c = 0; c < 4; ++c) {
#pragma unroll
    for (int j = 0; j < 8; ++j)
      bfrag[c][j] = (short)f2bf(wo[(c * 16 + half * 8 + j) * 64 + col]);
  }
  floatx16 acc;
#pragma unroll
  for (int i = 0; i < 16; ++i) acc[i] = 0.f;
  acc = __builtin_amdgcn_mfma_f32_32x32x16_bf16(a[0], bfrag[0], acc, 0, 0, 0);
  acc = __builtin_amdgcn_mfma_f32_32x32x16_bf16(a[1], bfrag[1], acc, 0, 0, 0);
  acc = __builtin_amdgcn_mfma_f32_32x32x16_bf16(a[2], bfrag[2], acc, 0, 0, 0);
  acc = __builtin_amdgcn_mfma_f32_32x32x16_bf16(a[3], bfrag[3], acc, 0, 0, 0);
  float bias = bo[col];
#pragma unroll
  for (int r = 0; r < 16; ++r) {
    int row = (r & 3) + 8 * (r >> 2) + 4 * half;
    sC[row * 68 + col] = acc[r] + tok[(size_t)(tbase + row) * 64 + col] + bias;
  }
  __syncthreads();
  // LN epilogue: 4 groups of 8 tokens, 2 cols/thread, width-32 shuffle
  int tg = tid >> 5, cg = tid & 31;
  int c0 = cg * 2, c1 = c0 + 1;
  float g0 = g[c0], g1 = g[c1], be0 = bb[c0], be1 = bb[c1];
#pragma unroll
  for (int i = 0; i < 8; ++i) {
    int lrow = tg * 8 + i;
    int token = tbase + lrow;
    float t0 = sC[lrow * 68 + c0];
    float t1 = sC[lrow * 68 + c1];
    float s1 = t0 + t1, s2 = t0 * t0 + t1 * t1;
    for (int off = 16; off; off >>= 1) {
      s1 += __shfl_xor(s1, off, 32);
      s2 += __shfl_xor(s2, off, 32);
    }
    float mu = s1 * (1.f / 64.f);
    float var = s2 * (1.f / 64.f) - mu * mu;
    float rs = rsqrtf(var + 1e-5f);
    tok2[token * 64 + c0] = t0;
    tok2[token * 64 + c1] = t1;
    h2[token * 64 + c0] = (t0 - mu) * rs * g0 + be0;
    h2[token * 64 + c1] = (t1 - mu) * rs * g1 + be1;
  }
}

// ---------------- FF phase 1 via MFMA: G = gelu(h2 @ W1 + b1), bf16 out ----------------
__global__ void __launch_bounds__(256) k_ff1(const float* __restrict__ h2,
                                             const float* __restrict__ w1,
                                             const float* __restrict__ b1,
                                             bf16* __restrict__ G) {
  int tid = threadIdx.x;
  int w = tid >> 6;
  int L = tid & 63;
  int half = L >> 5;
  int n = L & 31;
  int tbase = blockIdx.x * 32;

  short8 a[4];
  {
    const float* hrow = h2 + (size_t)(tbase + n) * 64 + half * 8;
#pragma unroll
    for (int c = 0; c < 4; ++c) {
      float4 f0 = *(const float4*)&hrow[c * 16];
      float4 f1 = *(const float4*)&hrow[c * 16 + 4];
      a[c][0] = (short)f2bf(f0.x); a[c][1] = (short)f2bf(f0.y);
      a[c][2] = (short)f2bf(f0.z); a[c][3] = (short)f2bf(f0.w);
      a[c][4] = (short)f2bf(f1.x); a[c][5] = (short)f2bf(f1.y);
      a[c][6] = (short)f2bf(f1.z); a[c][7] = (short)f2bf(f1.w);
    }
  }

#pragma unroll
  for (int ct = 0; ct < 2; ++ct) {
    int col = w * 64 + ct * 32 + n;
    short8 bfrag[4];
#pragma unroll
    for (int c = 0; c < 4; ++c) {
#pragma unroll
      for (int j = 0; j < 8; ++j)
        bfrag[c][j] = (short)f2bf(w1[(c * 16 + half * 8 + j) * 256 + col]);
    }
    floatx16 acc;
#pragma unroll
    for (int i = 0; i < 16; ++i) acc[i] = 0.f;
    acc = __builtin_amdgcn_mfma_f32_32x32x16_bf16(a[0], bfrag[0], acc, 0, 0, 0);
    acc = __builtin_amdgcn_mfma_f32_32x32x16_bf16(a[1], bfrag[1], acc, 0, 0, 0);
    acc = __builtin_amdgcn_mfma_f32_32x32x16_bf16(a[2], bfrag[2], acc, 0, 0, 0);
    acc = __builtin_amdgcn_mfma_f32_32x32x16_bf16(a[3], bfrag[3], acc, 0, 0, 0);
    float bias = b1[col];
#pragma unroll
    for (int r = 0; r < 16; ++r) {
      int row = (r & 3) + 8 * (r >> 2) + 4 * half;
      float xg = acc[r] + bias;
      float gl = 0.5f * xg * (1.f + erff(xg * 0.70710678118654752f));
      G[(size_t)(tbase + row) * 256 + col] = __float2bfloat16(gl);
    }
  }
}

// ---------------- Gavg: mean over T of the 8 G rows feeding each pool element ----------------
__global__ void k_gavg(const bf16* __restrict__ G, float* __restrict__ Gavg) {
  int blk = blockIdx.x;                 // 4608 = B*64*36
  int tid = threadIdx.x;                // column 0..255
  int b = blk / 2304;
  int rem = blk % 2304;
  int ch = rem / 36, jp = rem % 36;
  size_t gbase = ((size_t)b * 18432 + ch * 288 + jp) * 256 + tid;
  float s = 0.f;
#pragma unroll
  for (int t = 0; t < 8; ++t) s += __bfloat162float(G[gbase + (size_t)t * 36 * 256]);
  Gavg[(size_t)blk * 256 + tid] = s * 0.125f;
}

// ---------------- pool = mean_t(tok2) + Gavg @ W2 + b2 (FF2 folded 8x by linearity) ----------------
__global__ void __launch_bounds__(256) k_pool2(const float* __restrict__ Gavg,
                        const float* __restrict__ tok2, const float* __restrict__ w2,
                        const float* __restrict__ b2, float* __restrict__ pool) {
  __shared__ __align__(16) float sG[18 * 256];     // 18.4 KB
  __shared__ __align__(16) float sRed[4 * 18 * 64]; // 18.4 KB
  int blk = blockIdx.x;
  int b = blk / 128;
  int rem = blk % 128;
  int ch = rem >> 1, jph = rem & 1;
  int tid = threadIdx.x;
  size_t grow0 = ((size_t)(b * 64 + ch) * 36 + jph * 18) * 256;
  for (int e = tid; e < 1152; e += 256) {          // 18 rows x 64 float4
    int row = e >> 6, c4 = e & 63;
    *(float4*)&sG[row * 256 + c4 * 4] = *(const float4*)&Gavg[grow0 + row * 256 + c4 * 4];
  }
  __syncthreads();
  int kg = tid >> 6, dd = tid & 63;
  float acc[18];
#pragma unroll
  for (int i = 0; i < 18; ++i) acc[i] = 0.f;
  for (int k4 = 0; k4 < 16; ++k4) {
    int k = kg * 64 + k4 * 4;
    float w0 = w2[(k + 0) * 64 + dd];
    float w1 = w2[(k + 1) * 64 + dd];
    float w2v = w2[(k + 2) * 64 + dd];
    float w3 = w2[(k + 3) * 64 + dd];
#pragma unroll
    for (int i = 0; i < 18; ++i) {
      float4 gf = *(const float4*)&sG[i * 256 + k];   // wave-wide broadcast
      acc[i] += gf.x * w0 + gf.y * w1 + gf.z * w2v + gf.w * w3;
    }
  }
#pragma unroll
  for (int i = 0; i < 18; ++i) sRed[(kg * 18 + i) * 64 + dd] = acc[i];
  __syncthreads();
  for (int o = tid; o < 1152; o += 256) {
    int jp18 = o >> 6, d2 = o & 63;
    float gsum = sRed[(0 * 18 + jp18) * 64 + d2] + sRed[(1 * 18 + jp18) * 64 + d2]
               + sRed[(2 * 18 + jp18) * 64 + d2] + sRed[(3 * 18 + jp18) * 64 + d2];
    int p = (jph * 18 + jp18) * 64 + d2;
    size_t tbase = (size_t)b * 1179648 + (size_t)ch * 18432 + p;
    float ts = 0.f;
#pragma unroll
    for (int t = 0; t < 8; ++t) ts += tok2[tbase + t * 2304];
    pool[((size_t)(b * 64 + ch)) * HW + p] = ts * 0.125f + gsum + b2[d2];
  }
}

// ---------------- conv(5x5,pad2) + global-avg-pool folded ----------------
__global__ void __launch_bounds__(256) k_convsum(const float* __restrict__ pool,
                                                 const float* __restrict__ x,
                                                 const float* __restrict__ w,
                                                 float* __restrict__ partial) {
  int blk = blockIdx.x;          // b*65 + ch
  int b = blk / 65, ch = blk % 65;
  int tid = threadIdx.x;
  __shared__ float cls[25];
  __shared__ float red[256];
  if (tid < 25) {
    int ry = tid / 5, rx = tid % 5;
    int kh0 = (ry <= 2) ? 0 : (ry == 3 ? 1 : 2);
    int kh1 = (ry >= 2) ? 4 : (ry == 1 ? 3 : 2);
    int kw0 = (rx <= 2) ? 0 : (rx == 3 ? 1 : 2);
    int kw1 = (rx >= 2) ? 4 : (rx == 1 ? 3 : 2);
    float s = 0.f;
    for (int kh = kh0; kh <= kh1; ++kh)
      for (int kw = kw0; kw <= kw1; ++kw)
        s += w[ch * 25 + kh * 5 + kw];
    cls[tid] = s;
  }
  __syncthreads();
  const float* pc = (ch < 64) ? (pool + ((size_t)(b * 64 + ch)) * HW)
                              : (x + (size_t)b * 3 * S_ + 2 * S_);
  float acc = 0.f;
#pragma unroll
  for (int e = tid; e < HW; e += 256) {
    int iy = e / 48, ix = e % 48;
    int ry = (iy == 0) ? 0 : (iy == 1) ? 1 : (iy <= 45) ? 2 : (iy == 46) ? 3 : 4;
    int rx = (ix == 0) ? 0 : (ix == 1) ? 1 : (ix <= 45) ? 2 : (ix == 46) ? 3 : 4;
    acc += pc[e] * cls[ry * 5 + rx];
  }
  red[tid] = acc;
  __syncthreads();
  for (int s = 128; s; s >>= 1) {
    if (tid < s) red[tid] += red[tid + s];
    __syncthreads();
  }
  if (!tid) partial[blk] = red[0];
}

// ---------------- reduce 65 channel sums per b + readout ----------------
__global__ void k_final(const float* __restrict__ partial, const float* __restrict__ tgt_b,
                        const float* __restrict__ rd_w, const float* __restrict__ rd_b,
                        float* __restrict__ out) {
  int b = blockIdx.x;
  int lane = threadIdx.x;
  float s = (lane < 65) ? partial[b * 65 + lane] : 0.f;
  for (int off = 32; off; off >>= 1) s += __shfl_down(s, off, 64);
  __shared__ float r2;
  if (lane == 64) r2 = s;
  __syncthreads();
  if (!lane) {
    float tot = s + r2;
    float mean = tot / 2304.f + tgt_b[0];
    out[b] = mean * rd_w[0] + rd_b[0];
  }
}

extern "C" void kernel_launch(void* const* d_in, const int* in_sizes, int n_in,
                              void* d_out, int out_size, void* d_ws, size_t ws_size,
                              hipStream_t stream) {
  const float* x     = (const float*)d_in[0];
  const float* pre_w = (const float*)d_in[1];
  const float* pre_b = (const float*)d_in[2];
  const float* ln1_g = (const float*)d_in[3];
  const float* ln1_b = (const float*)d_in[4];
  const float* wq    = (const float*)d_in[5];
  const float* wk    = (const float*)d_in[6];
  const float* wv    = (const float*)d_in[7];
  const float* wo    = (const float*)d_in[8];
  const float* bo    = (const float*)d_in[9];
  const float* proj  = (const float*)d_in[10];
  const float* ln2_g = (const float*)d_in[11];
  const float* ln2_b = (const float*)d_in[12];
  const float* ff_w1 = (const float*)d_in[13];
  const float* ff_b1 = (const float*)d_in[14];
  const float* ff_w2 = (const float*)d_in[15];
  const float* ff_b2 = (const float*)d_in[16];
  const float* tgt_w = (const float*)d_in[17];
  const float* tgt_b = (const float*)d_in[18];
  const float* rd_w  = (const float*)d_in[19];
  const float* rd_b  = (const float*)d_in[20];
  float* out = (float*)d_out;

  float* ws = (float*)d_ws;
  float* tok   = ws;
  float* v     = ws + (size_t)BSD;
  float* q     = ws + 2 * (size_t)BSD;
  float* Gavg  = ws + 2 * (size_t)BSD;          // q dead after k_feat
  float* pool  = Gavg + 1179648;                // 294912 floats
  float* k     = ws + 3 * (size_t)BSD;
  float* h     = ws + 4 * (size_t)BSD;          // LN1 out; dead after k_qkv
  float* kp    = ws + 4 * (size_t)BSD;          // 2 BSD; written by k_feat after h dead
  float* qp    = ws + 6 * (size_t)BSD;          // 2 BSD; dead after k_attn
  bf16*  G     = (bf16*)(ws + 6 * (size_t)BSD); // 9.4M bf16 (reuses qp)
  float* ckv   = ws + 8 * (size_t)BSD;          // 2506752 floats; dead after k_attn
  float* tok2  = ws + 8 * (size_t)BSD;          // written by k_wo_ln (ckv dead)
  float* attnb = k;                             // k dead after k_feat
  float* h2    = ws + 4 * (size_t)BSD;          // kp dead after k_attn
  float* smalls = ws + 9 * (size_t)BSD + 147456;
  float* diagk = smalls;                        // 147456; k_feat -> k_csfin
  float* part  = diagk + BHS;                   // 2304 used
  float* gmax  = part + BHSM / 256;             // 1
  float* partial = gmax + 64;                   // 130

  k_preln<<<dim3(BS / 4), dim3(256), 0, stream>>>(x, pre_w, pre_b, ln1_g, ln1_b, tok, h);
  k_qkv<<<dim3(BS / 32), dim3(192), 0, stream>>>(h, wq, wk, wv, q, k, v);
  k_feat<<<dim3(BHS / 64), dim3(64), 0, stream>>>(q, k, proj, qp, kp, diagk, part);
  k_maxred<<<dim3(1), dim3(256), 0, stream>>>(part, gmax);
  k_csfin<<<dim3(BH * NC), dim3(256), 0, stream>>>(diagk, gmax, v, kp, ckv);
  k_prefix<<<dim3(BH * STATE / 256), dim3(256), 0, stream>>>(ckv);
  k_attn<<<dim3(BH * NC / 4), dim3(256), 0, stream>>>(qp, kp, v, ckv, attnb);
  k_wo_ln<<<dim3(BS / 32), dim3(128), 0, stream>>>(attnb, wo, bo, tok, ln2_g, ln2_b, tok2, h2);
  k_ff1<<<dim3(BS / 32), dim3(256), 0, stream>>>(h2, ff_w1, ff_b1, G);
  k_gavg<<<dim3(B_ * 64 * 36), dim3(256), 0, stream>>>(G, Gavg);
  k_pool2<<<dim3(B_ * 64 * 2), dim3(256), 0, stream>>>(Gavg, tok2, ff_w2, ff_b2, pool);
  k_convsum<<<dim3(B_ * 65), dim3(256), 0, stream>>>(pool, x, tgt_w, partial);
  k_final<<<dim3(B_), dim3(128), 0, stream>>>(partial, tgt_b, rd_w, rd_b, out);
}

// Round 13
// 240.380 us; speedup vs baseline: 1.3950x; 1.0715x over previous
//
#include <hip/hip_runtime.h>
#include <hip/hip_bf16.h>
#include <math.h>

typedef __hip_bfloat16 bf16;
typedef __attribute__((ext_vector_type(8))) short short8;
typedef __attribute__((ext_vector_type(16))) float floatx16;

// Problem constants
constexpr int B_   = 2;
constexpr int T_   = 8;
constexpr int HW   = 48 * 48;          // 2304
constexpr int S_   = T_ * HW;          // 18432
constexpr int D_   = 64;
constexpr int NH   = 4;
constexpr int DH   = 16;
constexpr int M_   = 32;
constexpr int BS   = B_ * S_;          // 36864 tokens
constexpr int BSD  = BS * D_;          // 2359296
constexpr int BH   = B_ * NH;          // 8 sequences
constexpr int BHS  = BH * S_;          // 147456 rows
constexpr int BHSM = BHS * M_;         // 4718592
constexpr int CHUNK = 32;
constexpr int NC   = S_ / CHUNK;       // 576 chunks per sequence
constexpr int STATE = M_ * DH + M_;    // 544 floats of scan state
constexpr float DN = 0.5f;                         // 16^-0.25
constexpr float RATIO = 0.17677669529663687f;      // 32^-0.5

__device__ __forceinline__ unsigned short f2bf(float f) {
  bf16 h = __float2bfloat16(f);
  return *reinterpret_cast<unsigned short*>(&h);
}

// ---------------- fused: 1x1x1 conv3d + softplus + LayerNorm1 ----------------
__global__ void k_preln(const float* __restrict__ x, const float* __restrict__ pw,
                        const float* __restrict__ pb, const float* __restrict__ g,
                        const float* __restrict__ bb,
                        float* __restrict__ tok, float* __restrict__ h) {
  int token = blockIdx.x * 4 + (threadIdx.x >> 6);
  int lane = threadIdx.x & 63;
  int f = token * 64 + lane;          // flat over B*D*S
  int b = f / (D_ * S_);
  int r = f % (D_ * S_);
  int d = r / S_;
  int pos = r % S_;
  const float* xb = x + b * 3 * S_ + pos;
  float a = xb[0] * pw[d * 3 + 0] + xb[S_] * pw[d * 3 + 1] + xb[2 * S_] * pw[d * 3 + 2]
          + pb[d];
  float t = fmaxf(a, 0.f) + log1pf(expf(-fabsf(a)));  // softplus
  tok[f] = t;
  float s1 = t, s2 = t * t;
  for (int off = 32; off; off >>= 1) {
    s1 += __shfl_xor(s1, off);
    s2 += __shfl_xor(s2, off);
  }
  float mu = s1 * (1.f / 64.f);
  float var = s2 * (1.f / 64.f) - mu * mu;
  float rs = rsqrtf(var + 1e-5f);
  h[f] = (t - mu) * rs * g[lane] + bb[lane];
}

// ---------------- QKV projections via MFMA: 3 waves = {wq,wk,wv}, 32 tokens/block ----------------
__global__ void __launch_bounds__(192) k_qkv(const float* __restrict__ h,
                      const float* __restrict__ wq, const float* __restrict__ wk,
                      const float* __restrict__ wv,
                      float* __restrict__ q, float* __restrict__ k, float* __restrict__ v) {
  int tid = threadIdx.x;
  int w = tid >> 6;                 // wave -> matrix
  int L = tid & 63;
  int half = L >> 5;
  int n = L & 31;
  int tbase = blockIdx.x * 32;
  const float* wm = (w == 0) ? wq : (w == 1) ? wk : wv;
  float* outm = (w == 0) ? q : (w == 1) ? k : v;

  short8 a[4];
  {
    const float* hrow = h + (size_t)(tbase + n) * 64 + half * 8;
#pragma unroll
    for (int c = 0; c < 4; ++c) {
      float4 f0 = *(const float4*)&hrow[c * 16];
      float4 f1 = *(const float4*)&hrow[c * 16 + 4];
      a[c][0] = (short)f2bf(f0.x); a[c][1] = (short)f2bf(f0.y);
      a[c][2] = (short)f2bf(f0.z); a[c][3] = (short)f2bf(f0.w);
      a[c][4] = (short)f2bf(f1.x); a[c][5] = (short)f2bf(f1.y);
      a[c][6] = (short)f2bf(f1.z); a[c][7] = (short)f2bf(f1.w);
    }
  }
#pragma unroll
  for (int ct = 0; ct < 2; ++ct) {
    int col = ct * 32 + n;
    short8 bfrag[4];
#pragma unroll
    for (int c = 0; c < 4; ++c) {
#pragma unroll
      for (int j = 0; j < 8; ++j)
        bfrag[c][j] = (short)f2bf(wm[(c * 16 + half * 8 + j) * 64 + col]);
    }
    floatx16 acc;
#pragma unroll
    for (int i = 0; i < 16; ++i) acc[i] = 0.f;
    acc = __builtin_amdgcn_mfma_f32_32x32x16_bf16(a[0], bfrag[0], acc, 0, 0, 0);
    acc = __builtin_amdgcn_mfma_f32_32x32x16_bf16(a[1], bfrag[1], acc, 0, 0, 0);
    acc = __builtin_amdgcn_mfma_f32_32x32x16_bf16(a[2], bfrag[2], acc, 0, 0, 0);
    acc = __builtin_amdgcn_mfma_f32_32x32x16_bf16(a[3], bfrag[3], acc, 0, 0, 0);
    int head = col >> 4, di = col & 15;
#pragma unroll
    for (int r = 0; r < 16; ++r) {
      int row = (r & 3) + 8 * (r >> 2) + 4 * half;
      int token = tbase + row;
      int b = token / S_, s = token % S_;
      outm[((size_t)(b * NH + head) * S_ + s) * DH + di] = acc[r];
    }
  }
}

// ---------------- feature map, row-per-thread: qp (bf16, final) + raw dash_k + diag_k + block max ----
__global__ void __launch_bounds__(64) k_feat(const float* __restrict__ q,
                      const float* __restrict__ k, const float* __restrict__ proj,
                      bf16* __restrict__ qpb, float* __restrict__ kp,
                      float* __restrict__ diagk, float* __restrict__ part) {
  __shared__ __align__(16) float sPT[16 * 32];   // proj^T [d][m]
  int tid = threadIdx.x;
  for (int e = tid; e < 512; e += 64) {
    int d = e >> 5, m = e & 31;
    sPT[d * 32 + m] = proj[m * 16 + d];          // m-fastest write: conflict-free
  }
  __syncthreads();
  int row = blockIdx.x * 64 + tid;
  float qv[16], kv[16];
  float dq = 0.f, dk = 0.f;
  {
    const float4* q4 = (const float4*)(q + (size_t)row * 16);
    const float4* k4 = (const float4*)(k + (size_t)row * 16);
#pragma unroll
    for (int i = 0; i < 4; ++i) {
      float4 t4 = q4[i];
      qv[4*i] = t4.x * DN; qv[4*i+1] = t4.y * DN; qv[4*i+2] = t4.z * DN; qv[4*i+3] = t4.w * DN;
      float4 u4 = k4[i];
      kv[4*i] = u4.x * DN; kv[4*i+1] = u4.y * DN; kv[4*i+2] = u4.z * DN; kv[4*i+3] = u4.w * DN;
    }
#pragma unroll
    for (int d = 0; d < 16; ++d) { dq += qv[d] * qv[d]; dk += kv[d] * kv[d]; }
    dq *= 0.5f; dk *= 0.5f;
  }
  float accq[32], acck[32];
#pragma unroll
  for (int m = 0; m < 32; ++m) { accq[m] = 0.f; acck[m] = 0.f; }
#pragma unroll
  for (int d = 0; d < 16; ++d) {
    float qd = qv[d], kd = kv[d];
    const float4* pr = (const float4*)&sPT[d * 32];
#pragma unroll
    for (int m4 = 0; m4 < 8; ++m4) {
      float4 p = pr[m4];                          // wave-uniform address: broadcast
      accq[4*m4+0] += qd * p.x; accq[4*m4+1] += qd * p.y;
      accq[4*m4+2] += qd * p.z; accq[4*m4+3] += qd * p.w;
      acck[4*m4+0] += kd * p.x; acck[4*m4+1] += kd * p.y;
      acck[4*m4+2] += kd * p.z; acck[4*m4+3] += kd * p.w;
    }
  }
  float mx = accq[0];
#pragma unroll
  for (int m = 1; m < 32; ++m) mx = fmaxf(mx, accq[m]);
#pragma unroll
  for (int m8 = 0; m8 < 4; ++m8) {
    float o[8];
#pragma unroll
    for (int j = 0; j < 8; ++j)
      o[j] = RATIO * (expf(accq[m8 * 8 + j] - dq - mx) + 1e-4f);
    uint4 pk;
    pk.x = (unsigned)f2bf(o[0]) | ((unsigned)f2bf(o[1]) << 16);
    pk.y = (unsigned)f2bf(o[2]) | ((unsigned)f2bf(o[3]) << 16);
    pk.z = (unsigned)f2bf(o[4]) | ((unsigned)f2bf(o[5]) << 16);
    pk.w = (unsigned)f2bf(o[6]) | ((unsigned)f2bf(o[7]) << 16);
    *(uint4*)&qpb[(size_t)row * 32 + m8 * 8] = pk;
  }
  float bmax = acck[0];
#pragma unroll
  for (int m = 1; m < 32; ++m) bmax = fmaxf(bmax, acck[m]);
#pragma unroll
  for (int m4 = 0; m4 < 8; ++m4)
    *(float4*)&kp[(size_t)row * 32 + m4 * 4] = *(float4*)&acck[4 * m4];
  diagk[row] = dk;
  for (int off = 32; off; off >>= 1) bmax = fmaxf(bmax, __shfl_xor(bmax, off));
  if (tid == 0) part[blockIdx.x] = bmax;
}

__global__ void k_maxred(const float* __restrict__ part, float* __restrict__ gmax) {
  float m = -3.4e38f;
  for (int i = threadIdx.x; i < BHS / 64; i += 256) m = fmaxf(m, part[i]);
  __shared__ float red[256];
  red[threadIdx.x] = m;
  __syncthreads();
  for (int s = 128; s; s >>= 1) {
    if (threadIdx.x < s) red[threadIdx.x] = fmaxf(red[threadIdx.x], red[threadIdx.x + s]);
    __syncthreads();
  }
  if (!threadIdx.x) gmax[0] = red[0];
}

// ---------------- kp-finalize (raw fp32 -> bf16 kpb) + per-chunk sums (LDS) ----------------
__global__ void __launch_bounds__(256) k_csfin(const float* __restrict__ diagk,
                      const float* __restrict__ gmax, const float* __restrict__ v,
                      const float* __restrict__ kp, bf16* __restrict__ kpb,
                      float* __restrict__ ckv) {
  __shared__ __align__(16) float sKp[CHUNK * 32];
  __shared__ __align__(16) float sVc[CHUNK * 16];
  int blk = blockIdx.x;
  int bh = blk / NC, c = blk % NC;
  int tid = threadIdx.x;
  int base = bh * S_ + c * CHUNK;
  float gm = gmax[0];
  {
    int row = tid >> 3, m4 = tid & 7;            // 32 rows x 8 float4
    float4 dash = *(const float4*)&kp[(size_t)(base + row) * 32 + m4 * 4];
    float dg = diagk[base + row] + gm;
    float4 fin;
    fin.x = RATIO * (expf(dash.x - dg) + 1e-4f);
    fin.y = RATIO * (expf(dash.y - dg) + 1e-4f);
    fin.z = RATIO * (expf(dash.z - dg) + 1e-4f);
    fin.w = RATIO * (expf(dash.w - dg) + 1e-4f);
    *(float4*)&sKp[row * 32 + m4 * 4] = fin;
    uint2 u;
    u.x = (unsigned)f2bf(fin.x) | ((unsigned)f2bf(fin.y) << 16);
    u.y = (unsigned)f2bf(fin.z) | ((unsigned)f2bf(fin.w) << 16);
    *(uint2*)&kpb[(size_t)(base + row) * 32 + m4 * 4] = u;
  }
  if (tid < 128) {                               // V: 32 rows x 4 float4
    int row = tid >> 2, c4 = tid & 3;
    *(float4*)&sVc[row * 16 + c4 * 4] = *(const float4*)&v[(size_t)(base + row) * 16 + c4 * 4];
  }
  __syncthreads();
  int m0 = tid >> 4, d0 = tid & 15;
  int m1 = m0 + 16;
  float a0 = 0.f, a1 = 0.f, az0 = 0.f, az1 = 0.f;
  for (int t = 0; t < CHUNK; ++t) {
    float k0 = sKp[t * 32 + m0];
    float k1 = sKp[t * 32 + m1];
    float vv = sVc[t * 16 + d0];
    a0 += k0 * vv;
    a1 += k1 * vv;
    if (d0 == 0) { az0 += k0; az1 += k1; }
  }
  float* outp = ckv + (size_t)blk * STATE;
  outp[m0 * 16 + d0] = a0;
  outp[m1 * 16 + d0] = a1;
  if (d0 == 0) { outp[512 + m0] = az0; outp[512 + m1] = az1; }
}

// ---------------- exclusive prefix over chunks (in place), one scan-column per thread ----------------
__global__ void k_prefix(float* __restrict__ ckv) {
  int idx = blockIdx.x * 256 + threadIdx.x;      // 17 blocks x 256 = 4352 = BH*544
  int bh = idx / STATE, c = idx % STATE;
  float run = 0.f;
  for (int j0 = 0; j0 < NC; j0 += 16) {
    float tb[16];
#pragma unroll
    for (int jj = 0; jj < 16; ++jj) tb[jj] = ckv[((size_t)bh * NC + j0 + jj) * STATE + c];
#pragma unroll
    for (int jj = 0; jj < 16; ++jj) {
      ckv[((size_t)bh * NC + j0 + jj) * STATE + c] = run;
      run += tb[jj];
    }
  }
}

// ---------------- within-chunk causal attention via MFMA (CHUNK=32; 4 chunks/block, 1 wave each) ----
__global__ void __launch_bounds__(256) k_attn(const bf16* __restrict__ qpb,
                                              const bf16* __restrict__ kpb,
                                              const float* __restrict__ v,
                                              const float* __restrict__ ckv,
                                              float* __restrict__ attn) {
  __shared__ __align__(16) float sP[4][32 * 33 + 4];
  int tid = threadIdx.x;
  int w = tid >> 6;                 // wave -> chunk
  int L = tid & 63;
  int half = L >> 5;
  int n = L & 31;
  int chunk = blockIdx.x * 4 + w;
  int bh = chunk / NC, c = chunk % NC;
  int base = bh * S_ + c * CHUNK;

  short8 a1 = *(const short8*)(qpb + (size_t)(base + n) * 32 + half * 8);
  short8 a2 = *(const short8*)(qpb + (size_t)(base + n) * 32 + 16 + half * 8);
  short8 b1 = *(const short8*)(kpb + (size_t)(base + n) * 32 + half * 8);
  short8 b2 = *(const short8*)(kpb + (size_t)(base + n) * 32 + 16 + half * 8);

  floatx16 P;
#pragma unroll
  for (int i = 0; i < 16; ++i) P[i] = 0.f;
  P = __builtin_amdgcn_mfma_f32_32x32x16_bf16(a1, b1, P, 0, 0, 0);
  P = __builtin_amdgcn_mfma_f32_32x32x16_bf16(a2, b2, P, 0, 0, 0);

  float* sp = &sP[w][0];
#pragma unroll
  for (int r = 0; r < 16; ++r) {
    int i = (r & 3) + 8 * (r >> 2) + 4 * half;
    sp[i * 33 + n] = (n <= i) ? P[r] : 0.f;
  }
  __syncthreads();
  short8 pa1, pa2;
#pragma unroll
  for (int j = 0; j < 8; ++j) {
    pa1[j] = (short)f2bf(sp[n * 33 + half * 8 + j]);
    pa2[j] = (short)f2bf(sp[n * 33 + 16 + half * 8 + j]);
  }

  const float* cs = ckv + (size_t)chunk * STATE;
  short8 vb1, vb2, sb1, sb2;
#pragma unroll
  for (int j = 0; j < 8; ++j) {
    int t1 = half * 8 + j, t2 = 16 + half * 8 + j;
    float x1 = (n < 16) ? v[(size_t)(base + t1) * 16 + n] : (n == 16 ? 1.f : 0.f);
    float x2 = (n < 16) ? v[(size_t)(base + t2) * 16 + n] : (n == 16 ? 1.f : 0.f);
    vb1[j] = (short)f2bf(x1);
    vb2[j] = (short)f2bf(x2);
    float y1 = (n < 16) ? cs[t1 * 16 + n] : (n == 16 ? cs[512 + t1] : 0.f);
    float y2 = (n < 16) ? cs[t2 * 16 + n] : (n == 16 ? cs[512 + t2] : 0.f);
    sb1[j] = (short)f2bf(y1);
    sb2[j] = (short)f2bf(y2);
  }

  floatx16 O;
#pragma unroll
  for (int i = 0; i < 16; ++i) O[i] = 0.f;
  O = __builtin_amdgcn_mfma_f32_32x32x16_bf16(pa1, vb1, O, 0, 0, 0);
  O = __builtin_amdgcn_mfma_f32_32x32x16_bf16(pa2, vb2, O, 0, 0, 0);
  O = __builtin_amdgcn_mfma_f32_32x32x16_bf16(a1, sb1, O, 0, 0, 0);
  O = __builtin_amdgcn_mfma_f32_32x32x16_bf16(a2, sb2, O, 0, 0, 0);

  int srcl = 16 + 32 * half;
  float res[16];
#pragma unroll
  for (int r = 0; r < 16; ++r) {
    float den = __shfl(O[r], srcl, 64);
    res[r] = O[r] / den;
  }
  if (n < 16) {
    int b = bh >> 2, head = bh & 3;
#pragma unroll
    for (int r = 0; r < 16; ++r) {
      int i = (r & 3) + 8 * (r >> 2) + 4 * half;
      attn[((size_t)(b * S_ + c * CHUNK + i)) * 64 + head * 16 + n] = res[r];
    }
  }
}

// ---------------- attn @ wo + bo + residual + LayerNorm2 via MFMA ----------------
__global__ void __launch_bounds__(128) k_wo_ln(const float* __restrict__ attn,
                        const float* __restrict__ wo, const float* __restrict__ bo,
                        const float* __restrict__ tok, const float* __restrict__ g,
                        const float* __restrict__ bb,
                        float* __restrict__ tok2, float* __restrict__ h2) {
  __shared__ __align__(16) float sC[32 * 68];
  int tid = threadIdx.x;
  int w = tid >> 6;                 // coltile
  int L = tid & 63;
  int half = L >> 5;
  int n = L & 31;
  int tbase = blockIdx.x * 32;

  short8 a[4];
  {
    const float* arow = attn + (size_t)(tbase + n) * 64 + half * 8;
#pragma unroll
    for (int c = 0; c < 4; ++c) {
      float4 f0 = *(const float4*)&arow[c * 16];
      float4 f1 = *(const float4*)&arow[c * 16 + 4];
      a[c][0] = (short)f2bf(f0.x); a[c][1] = (short)f2bf(f0.y);
      a[c][2] = (short)f2bf(f0.z); a[c][3] = (short)f2bf(f0.w);
      a[c][4] = (short)f2bf(f1.x); a[c][5] = (short)f2bf(f1.y);
      a[c][6] = (short)f2bf(f1.z); a[c][7] = (short)f2bf(f1.w);
    }
  }
  int col = w * 32 + n;
  short8 bfrag[4];
#pragma unroll
  for (int c = 0; c < 4; ++c) {
#pragma unroll
    for (int j = 0; j < 8; ++j)
      bfrag[c][j] = (short)f2bf(wo[(c * 16 + half * 8 + j) * 64 + col]);
  }
  floatx16 acc;
#pragma unroll
  for (int i = 0; i < 16; ++i) acc[i] = 0.f;
  acc = __builtin_amdgcn_mfma_f32_32x32x16_bf16(a[0], bfrag[0], acc, 0, 0, 0);
  acc = __builtin_amdgcn_mfma_f32_32x32x16_bf16(a[1], bfrag[1], acc, 0, 0, 0);
  acc = __builtin_amdgcn_mfma_f32_32x32x16_bf16(a[2], bfrag[2], acc, 0, 0, 0);
  acc = __builtin_amdgcn_mfma_f32_32x32x16_bf16(a[3], bfrag[3], acc, 0, 0, 0);
  float bias = bo[col];
#pragma unroll
  for (int r = 0; r < 16; ++r) {
    int row = (r & 3) + 8 * (r >> 2) + 4 * half;
    sC[row * 68 + col] = acc[r] + tok[(size_t)(tbase + row) * 64 + col] + bias;
  }
  __syncthreads();
  int tg = tid >> 5, cg = tid & 31;
  int c0 = cg * 2, c1 = c0 + 1;
  float g0 = g[c0], g1 = g[c1], be0 = bb[c0], be1 = bb[c1];
#pragma unroll
  for (int i = 0; i < 8; ++i) {
    int lrow = tg * 8 + i;
    int token = tbase + lrow;
    float t0 = sC[lrow * 68 + c0];
    float t1 = sC[lrow * 68 + c1];
    float s1 = t0 + t1, s2 = t0 * t0 + t1 * t1;
    for (int off = 16; off; off >>= 1) {
      s1 += __shfl_xor(s1, off, 32);
      s2 += __shfl_xor(s2, off, 32);
    }
    float mu = s1 * (1.f / 64.f);
    float var = s2 * (1.f / 64.f) - mu * mu;
    float rs = rsqrtf(var + 1e-5f);
    tok2[token * 64 + c0] = t0;
    tok2[token * 64 + c1] = t1;
    h2[token * 64 + c0] = (t0 - mu) * rs * g0 + be0;
    h2[token * 64 + c1] = (t1 - mu) * rs * g1 + be1;
  }
}

// ---------------- FF1 + Gavg fused via MFMA: Gavg = mean_t gelu(h2 @ W1 + b1) ----------------
// Block = (b, ch, jp0 = 4*j9); A rows n = jp_local*8 + t -> token b*18432 + ch*288 + t*36 + jp0+jp_local.
// After MFMA+gelu, rows 8j..8j+7 live in regs 4j..4j+3 across the two lane-halves:
// in-register sum + shfl_xor(32) gives the t-mean; G is never materialized.
__global__ void __launch_bounds__(256) k_ffg(const float* __restrict__ h2,
                                             const float* __restrict__ w1,
                                             const float* __restrict__ b1,
                                             float* __restrict__ Gavg) {
  int tid = threadIdx.x;
  int w = tid >> 6;
  int L = tid & 63;
  int half = L >> 5;
  int n = L & 31;
  int blk = blockIdx.x;                 // B*64*9 = 1152
  int b = blk / 576;
  int rem = blk % 576;
  int ch = rem / 9;
  int jp0 = (rem % 9) * 4;
  int token_n = b * 18432 + ch * 288 + (n & 7) * 36 + jp0 + (n >> 3);

  short8 a[4];
  {
    const float* hrow = h2 + (size_t)token_n * 64 + half * 8;
#pragma unroll
    for (int c = 0; c < 4; ++c) {
      float4 f0 = *(const float4*)&hrow[c * 16];
      float4 f1 = *(const float4*)&hrow[c * 16 + 4];
      a[c][0] = (short)f2bf(f0.x); a[c][1] = (short)f2bf(f0.y);
      a[c][2] = (short)f2bf(f0.z); a[c][3] = (short)f2bf(f0.w);
      a[c][4] = (short)f2bf(f1.x); a[c][5] = (short)f2bf(f1.y);
      a[c][6] = (short)f2bf(f1.z); a[c][7] = (short)f2bf(f1.w);
    }
  }
  size_t gbase = ((size_t)(b * 64 + ch) * 36 + jp0);
#pragma unroll
  for (int ct = 0; ct < 2; ++ct) {
    int col = w * 64 + ct * 32 + n;
    short8 bfrag[4];
#pragma unroll
    for (int c = 0; c < 4; ++c) {
#pragma unroll
      for (int j = 0; j < 8; ++j)
        bfrag[c][j] = (short)f2bf(w1[(c * 16 + half * 8 + j) * 256 + col]);
    }
    floatx16 acc;
#pragma unroll
    for (int i = 0; i < 16; ++i) acc[i] = 0.f;
    acc = __builtin_amdgcn_mfma_f32_32x32x16_bf16(a[0], bfrag[0], acc, 0, 0, 0);
    acc = __builtin_amdgcn_mfma_f32_32x32x16_bf16(a[1], bfrag[1], acc, 0, 0, 0);
    acc = __builtin_amdgcn_mfma_f32_32x32x16_bf16(a[2], bfrag[2], acc, 0, 0, 0);
    acc = __builtin_amdgcn_mfma_f32_32x32x16_bf16(a[3], bfrag[3], acc, 0, 0, 0);
    float bias = b1[col];
#pragma unroll
    for (int j = 0; j < 4; ++j) {          // jp_local
      float s = 0.f;
#pragma unroll
      for (int rr = 0; rr < 4; ++rr) {
        float xg = acc[j * 4 + rr] + bias;
        s += 0.5f * xg * (1.f + erff(xg * 0.70710678118654752f));
      }
      s += __shfl_xor(s, 32);              // combine the two lane-halves (t 0..3 | 4..7)
      if (half == 0)
        Gavg[(gbase + j) * 256 + col] = s * 0.125f;
    }
  }
}

// ---------------- pool = mean_t(tok2) + Gavg @ W2 + b2 (FF2 folded 8x by linearity) ----------------
__global__ void __launch_bounds__(256) k_pool2(const float* __restrict__ Gavg,
                        const float* __restrict__ tok2, const float* __restrict__ w2,
                        const float* __restrict__ b2, float* __restrict__ pool) {
  __shared__ __align__(16) float sG[18 * 256];     // 18.4 KB
  __shared__ __align__(16) float sRed[4 * 18 * 64]; // 18.4 KB
  int blk = blockIdx.x;
  int b = blk / 128;
  int rem = blk % 128;
  int ch = rem >> 1, jph = rem & 1;
  int tid = threadIdx.x;
  size_t grow0 = ((size_t)(b * 64 + ch) * 36 + jph * 18) * 256;
  for (int e = tid; e < 1152; e += 256) {          // 18 rows x 64 float4
    int row = e >> 6, c4 = e & 63;
    *(float4*)&sG[row * 256 + c4 * 4] = *(const float4*)&Gavg[grow0 + row * 256 + c4 * 4];
  }
  __syncthreads();
  int kg = tid >> 6, dd = tid & 63;
  float acc[18];
#pragma unroll
  for (int i = 0; i < 18; ++i) acc[i] = 0.f;
  for (int k4 = 0; k4 < 16; ++k4) {
    int k = kg * 64 + k4 * 4;
    float w0 = w2[(k + 0) * 64 + dd];
    float w1 = w2[(k + 1) * 64 + dd];
    float w2v = w2[(k + 2) * 64 + dd];
    float w3 = w2[(k + 3) * 64 + dd];
#pragma unroll
    for (int i = 0; i < 18; ++i) {
      float4 gf = *(const float4*)&sG[i * 256 + k];   // wave-wide broadcast
      acc[i] += gf.x * w0 + gf.y * w1 + gf.z * w2v + gf.w * w3;
    }
  }
#pragma unroll
  for (int i = 0; i < 18; ++i) sRed[(kg * 18 + i) * 64 + dd] = acc[i];
  __syncthreads();
  for (int o = tid; o < 1152; o += 256) {
    int jp18 = o >> 6, d2 = o & 63;
    float gsum = sRed[(0 * 18 + jp18) * 64 + d2] + sRed[(1 * 18 + jp18) * 64 + d2]
               + sRed[(2 * 18 + jp18) * 64 + d2] + sRed[(3 * 18 + jp18) * 64 + d2];
    int p = (jph * 18 + jp18) * 64 + d2;
    size_t tbase = (size_t)b * 1179648 + (size_t)ch * 18432 + p;
    float ts = 0.f;
#pragma unroll
    for (int t = 0; t < 8; ++t) ts += tok2[tbase + t * 2304];
    pool[((size_t)(b * 64 + ch)) * HW + p] = ts * 0.125f + gsum + b2[d2];
  }
}

// ---------------- conv(5x5,pad2) + global-avg-pool folded ----------------
__global__ void __launch_bounds__(256) k_convsum(const float* __restrict__ pool,
                                                 const float* __restrict__ x,
                                                 const float* __restrict__ w,
                                                 float* __restrict__ partial) {
  int blk = blockIdx.x;          // b*65 + ch
  int b = blk / 65, ch = blk % 65;
  int tid = threadIdx.x;
  __shared__ float cls[25];
  __shared__ float red[256];
  if (tid < 25) {
    int ry = tid / 5, rx = tid % 5;
    int kh0 = (ry <= 2) ? 0 : (ry == 3 ? 1 : 2);
    int kh1 = (ry >= 2) ? 4 : (ry == 1 ? 3 : 2);
    int kw0 = (rx <= 2) ? 0 : (rx == 3 ? 1 : 2);
    int kw1 = (rx >= 2) ? 4 : (rx == 1 ? 3 : 2);
    float s = 0.f;
    for (int kh = kh0; kh <= kh1; ++kh)
      for (int kw = kw0; kw <= kw1; ++kw)
        s += w[ch * 25 + kh * 5 + kw];
    cls[tid] = s;
  }
  __syncthreads();
  const float* pc = (ch < 64) ? (pool + ((size_t)(b * 64 + ch)) * HW)
                              : (x + (size_t)b * 3 * S_ + 2 * S_);
  float acc = 0.f;
#pragma unroll
  for (int e = tid; e < HW; e += 256) {
    int iy = e / 48, ix = e % 48;
    int ry = (iy == 0) ? 0 : (iy == 1) ? 1 : (iy <= 45) ? 2 : (iy == 46) ? 3 : 4;
    int rx = (ix == 0) ? 0 : (ix == 1) ? 1 : (ix <= 45) ? 2 : (ix == 46) ? 3 : 4;
    acc += pc[e] * cls[ry * 5 + rx];
  }
  red[tid] = acc;
  __syncthreads();
  for (int s = 128; s; s >>= 1) {
    if (tid < s) red[tid] += red[tid + s];
    __syncthreads();
  }
  if (!tid) partial[blk] = red[0];
}

// ---------------- reduce 65 channel sums per b + readout ----------------
__global__ void k_final(const float* __restrict__ partial, const float* __restrict__ tgt_b,
                        const float* __restrict__ rd_w, const float* __restrict__ rd_b,
                        float* __restrict__ out) {
  int b = blockIdx.x;
  int lane = threadIdx.x;
  float s = (lane < 65) ? partial[b * 65 + lane] : 0.f;
  for (int off = 32; off; off >>= 1) s += __shfl_down(s, off, 64);
  __shared__ float r2;
  if (lane == 64) r2 = s;
  __syncthreads();
  if (!lane) {
    float tot = s + r2;
    float mean = tot / 2304.f + tgt_b[0];
    out[b] = mean * rd_w[0] + rd_b[0];
  }
}

extern "C" void kernel_launch(void* const* d_in, const int* in_sizes, int n_in,
                              void* d_out, int out_size, void* d_ws, size_t ws_size,
                              hipStream_t stream) {
  const float* x     = (const float*)d_in[0];
  const float* pre_w = (const float*)d_in[1];
  const float* pre_b = (const float*)d_in[2];
  const float* ln1_g = (const float*)d_in[3];
  const float* ln1_b = (const float*)d_in[4];
  const float* wq    = (const float*)d_in[5];
  const float* wk    = (const float*)d_in[6];
  const float* wv    = (const float*)d_in[7];
  const float* wo    = (const float*)d_in[8];
  const float* bo    = (const float*)d_in[9];
  const float* proj  = (const float*)d_in[10];
  const float* ln2_g = (const float*)d_in[11];
  const float* ln2_b = (const float*)d_in[12];
  const float* ff_w1 = (const float*)d_in[13];
  const float* ff_b1 = (const float*)d_in[14];
  const float* ff_w2 = (const float*)d_in[15];
  const float* ff_b2 = (const float*)d_in[16];
  const float* tgt_w = (const float*)d_in[17];
  const float* tgt_b = (const float*)d_in[18];
  const float* rd_w  = (const float*)d_in[19];
  const float* rd_b  = (const float*)d_in[20];
  float* out = (float*)d_out;

  float* ws = (float*)d_ws;
  // BSD-unit layout:
  // 0 tok | 1 v | 2 q (dead after feat) -> Gavg + pool | 3 k/attnb
  // 4-5 kp raw (dead after csfin) -> h2 at 4 | 6 qpb (bf16) | 7 kpb (bf16)
  // 8 ckv (dead after attn) -> tok2 | 9+ smalls
  float* tok   = ws;
  float* v     = ws + (size_t)BSD;
  float* q     = ws + 2 * (size_t)BSD;
  float* Gavg  = ws + 2 * (size_t)BSD;          // 1179648 floats (q dead after k_feat)
  float* pool  = Gavg + 1179648;                // 294912 floats
  float* k     = ws + 3 * (size_t)BSD;
  float* h     = ws + 4 * (size_t)BSD;          // LN1 out; dead after k_qkv
  float* kp    = ws + 4 * (size_t)BSD;          // 2 BSD raw dash; dead after k_csfin
  bf16*  qpb   = (bf16*)(ws + 6 * (size_t)BSD); // BHSM bf16
  bf16*  kpb   = (bf16*)(ws + 7 * (size_t)BSD); // BHSM bf16
  float* ckv   = ws + 8 * (size_t)BSD;          // 2506752 floats; dead after k_attn
  float* tok2  = ws + 8 * (size_t)BSD;          // written by k_wo_ln (ckv dead)
  float* attnb = k;                             // k dead after k_feat
  float* h2    = ws + 4 * (size_t)BSD;          // kp dead after k_csfin
  float* smalls = ws + 9 * (size_t)BSD + 147456;
  float* diagk = smalls;                        // 147456
  float* part  = diagk + BHS;                   // 2304 used
  float* gmax  = part + BHSM / 256;             // 1
  float* partial = gmax + 64;                   // 130

  k_preln<<<dim3(BS / 4), dim3(256), 0, stream>>>(x, pre_w, pre_b, ln1_g, ln1_b, tok, h);
  k_qkv<<<dim3(BS / 32), dim3(192), 0, stream>>>(h, wq, wk, wv, q, k, v);
  k_feat<<<dim3(BHS / 64), dim3(64), 0, stream>>>(q, k, proj, qpb, kp, diagk, part);
  k_maxred<<<dim3(1), dim3(256), 0, stream>>>(part, gmax);
  k_csfin<<<dim3(BH * NC), dim3(256), 0, stream>>>(diagk, gmax, v, kp, kpb, ckv);
  k_prefix<<<dim3(BH * STATE / 256), dim3(256), 0, stream>>>(ckv);
  k_attn<<<dim3(BH * NC / 4), dim3(256), 0, stream>>>(qpb, kpb, v, ckv, attnb);
  k_wo_ln<<<dim3(BS / 32), dim3(128), 0, stream>>>(attnb, wo, bo, tok, ln2_g, ln2_b, tok2, h2);
  k_ffg<<<dim3(B_ * 64 * 9), dim3(256), 0, stream>>>(h2, ff_w1, ff_b1, Gavg);
  k_pool2<<<dim3(B_ * 64 * 2), dim3(256), 0, stream>>>(Gavg, tok2, ff_w2, ff_b2, pool);
  k_convsum<<<dim3(B_ * 65), dim3(256), 0, stream>>>(pool, x, tgt_w, partial);
  k_final<<<dim3(B_), dim3(128), 0, stream>>>(partial, tgt_b, rd_w, rd_b, out);
}